// Round 4
// baseline (613.150 us; speedup 1.0000x reference)
//
#include <hip/hip_runtime.h>

typedef __attribute__((ext_vector_type(8))) short bf16x8;
typedef __attribute__((ext_vector_type(4))) float f32x4;

__device__ inline float bf2f(unsigned short u) {
    union { float f; unsigned int i; } v; v.i = ((unsigned int)u) << 16; return v.f;
}
__device__ inline unsigned short f2bf(float f) {
    union { float f; unsigned int u; } v; v.f = f;
    unsigned int x = v.u;
    unsigned int r = x + 0x7FFFu + ((x >> 16) & 1u);
    return (unsigned short)(r >> 16);
}
// order-preserving float <-> uint for atomicMax
__device__ inline unsigned int fenc(float x) {
    union { float f; unsigned int u; } v; v.f = x;
    return (v.u & 0x80000000u) ? ~v.u : (v.u | 0x80000000u);
}
__device__ inline float fdec(unsigned int k) {
    union { float f; unsigned int u; } v;
    v.u = (k & 0x80000000u) ? (k & 0x7FFFFFFFu) : ~k;
    return v.f;
}
// dual-format loads: f32flag ? float32 buffer : bf16 buffer
__device__ inline float ldf(const void* p, size_t i, int f32) {
    return f32 ? ((const float*)p)[i] : bf2f(((const unsigned short*)p)[i]);
}
// i64flag ? int64 buffer (values < 2^31, take low word) : int32 buffer
__device__ inline int ldi(const int* p, size_t i, int i64) {
    return i64 ? p[2 * i] : p[i];
}

// ---------------- format detection (device-side, deterministic) ----------------
__global__ __launch_bounds__(256)
void k_detect(const unsigned short* __restrict__ xu, int xstride,
              const int* __restrict__ ei, int estride, int* __restrict__ flags) {
    __shared__ int cnt, orv;
    if (threadIdx.x == 0) { cnt = 0; orv = 0; }
    __syncthreads();
    int c = 0, o = 0;
    for (int s = 0; s < 4; ++s) {
        int j = threadIdx.x * 4 + s;               // 0..1023
        size_t k = (size_t)j * xstride;            // < xelems/2
        unsigned short u = xu[2 * k];              // even ushort
        int e = (u >> 7) & 0xFF;
        if (e >= 100 && e <= 140) ++c;             // sane bf16 exponent?
        size_t idx = (size_t)j * estride;          // < E
        o |= ei[2 * idx + 1];                      // odd word
    }
    atomicAdd(&cnt, c); atomicOr(&orv, o);
    __syncthreads();
    if (threadIdx.x == 0) {
        flags[0] = (cnt < 768) ? 1 : 0;   // 1 => floats are f32
        flags[1] = (orv == 0) ? 1 : 0;    // 1 => ints are int64
    }
}

// ---------------- zero scratch (replaces 5 memsets) ----------------
__global__ void k_zero(int* __restrict__ hist, int* __restrict__ cursor,
                       float* __restrict__ psum, unsigned int* __restrict__ pkey,
                       int* __restrict__ pcnt, int N) {
    int t = blockIdx.x * 256 + threadIdx.x;
    if (t < N) hist[t] = 0;
    else if (t < 2 * N) cursor[t - N] = 0;
    else if (t < 2 * N + 16384) psum[t - 2 * N] = 0.f;
    else if (t < 2 * N + 32768) pkey[t - 2 * N - 16384] = 0u;
    else if (t < 2 * N + 32768 + 64) pcnt[t - 2 * N - 32768] = 0;
}

// ---------------- X -> bf16 conversion (or copy if already bf16) ----------------
__global__ __launch_bounds__(256)
void k_cvt(const void* __restrict__ X, unsigned short* __restrict__ Xb,
           size_t nelem, const int* __restrict__ flags) {
    int f = flags[0];
    size_t i = ((size_t)blockIdx.x * 256 + threadIdx.x) * 8;
    if (i >= nelem) return;
    if (f) {
        const float* s = (const float*)X + i;
        float4 f0 = *(const float4*)s;
        float4 f1 = *(const float4*)(s + 4);
        int4 o;
        o.x = (int)f2bf(f0.x) | ((int)f2bf(f0.y) << 16);
        o.y = (int)f2bf(f0.z) | ((int)f2bf(f0.w) << 16);
        o.z = (int)f2bf(f1.x) | ((int)f2bf(f1.y) << 16);
        o.w = (int)f2bf(f1.z) | ((int)f2bf(f1.w) << 16);
        *(int4*)(Xb + i) = o;
    } else {
        *(int4*)(Xb + i) = *(const int4*)((const unsigned short*)X + i);
    }
}

// ---------------- CSR build ----------------
__global__ void k_hist(const int* __restrict__ ei, int E, int N,
                       int* __restrict__ hist, const int* __restrict__ flags) {
    int e = blockIdx.x * 256 + threadIdx.x;
    if (e >= E) return;
    int i64 = flags[1];
    int d = ldi(ei, (size_t)E + e, i64); d = d < 0 ? 0 : (d >= N ? N - 1 : d);
    atomicAdd(&hist[d], 1);
}

__global__ void k_dinv(const int* __restrict__ hist, float* __restrict__ dinv, int N) {
    int i = blockIdx.x * 256 + threadIdx.x;
    if (i < N) dinv[i] = rsqrtf((float)(hist[i] + 1));
}

__global__ __launch_bounds__(1024)
void k_scan(const int* __restrict__ hist, int* __restrict__ rowptr, int N) {
    __shared__ int ssum[1024];
    int t = threadIdx.x;
    int chunk = (N + 1023) / 1024;
    int lo = t * chunk, hi = lo + chunk; if (hi > N) hi = N; if (lo > N) lo = N;
    int s = 0;
#pragma unroll 4
    for (int i = lo; i < hi; ++i) s += hist[i];
    ssum[t] = s;
    __syncthreads();
    for (int off = 1; off < 1024; off <<= 1) {
        int v = (t >= off) ? ssum[t - off] : 0;
        __syncthreads();
        ssum[t] += v;
        __syncthreads();
    }
    int run = ssum[t] - s;
    for (int i = lo; i < hi; ++i) { rowptr[i] = run; run += hist[i]; }
    if (t == 1023) rowptr[N] = ssum[1023];
}

__global__ void k_scatter(const int* __restrict__ ei, int E, int N,
                          const int* __restrict__ rowptr, int* __restrict__ cursor,
                          int* __restrict__ col, const int* __restrict__ flags) {
    int e = blockIdx.x * 256 + threadIdx.x;
    if (e >= E) return;
    int i64 = flags[1];
    int s = ldi(ei, (size_t)e, i64);     s = s < 0 ? 0 : (s >= N ? N - 1 : s);
    int d = ldi(ei, (size_t)E + e, i64); d = d < 0 ? 0 : (d >= N ? N - 1 : d);
    int pos = rowptr[d] + atomicAdd(&cursor[d], 1);
    col[pos] = s;
}

// ---------------- weight folding: tiled 64x64 LDS GEMM ----------------
// Products Q[i] = pre_w[i] @ gcn_w[i] (256x256 each), i in {0,1,2,3}:
// which=0: Wt0[n*256+k]     = 2*Q0[k][n] + Q1[k][n]
// which=1: Wt1[n*512+k]     = 2*Q2[k][n]
// which=2: Wt1[n*512+256+k] =   Q3[k][n]
// grid (16 tiles, 3 which), 256 thr; block computes 64(k) x 64(n) tile.
__global__ __launch_bounds__(256)
void k_prepw(const void* __restrict__ pre_w, const void* __restrict__ gcn_w,
             unsigned short* __restrict__ Wt0, unsigned short* __restrict__ Wt1,
             const int* __restrict__ flags) {
    __shared__ float sP[2][64][64];
    __shared__ float sG[2][64][64];
    const int which = blockIdx.y;
    const int k0 = (blockIdx.x & 3) * 64;
    const int n0 = (blockIdx.x >> 2) * 64;
    const int f = flags[0];
    const int t = threadIdx.x;
    const int tn = t & 15, tk = t >> 4;      // 16 x 16 thread grid
    size_t pbase0, gbase0, pbase1 = 0, gbase1 = 0;
    if (which == 0)      { pbase0 = 0;         gbase0 = 0;         pbase1 = 65536; gbase1 = 65536; }
    else if (which == 1) { pbase0 = 2 * 65536; gbase0 = 2 * 65536; }
    else                 { pbase0 = 3 * 65536; gbase0 = 3 * 65536; }

    float acc0[4][4] = {};
    float acc1[4][4] = {};
    for (int mc = 0; mc < 4; ++mc) {
        const int m0 = mc * 64;
        __syncthreads();
#pragma unroll
        for (int q = 0; q < 16; ++q) {
            int idx = q * 256 + t;
            int r = idx >> 6, c = idx & 63;
            sP[0][r][c] = ldf(pre_w, pbase0 + (size_t)(k0 + r) * 256 + m0 + c, f);
            sG[0][r][c] = ldf(gcn_w, gbase0 + (size_t)(m0 + r) * 256 + n0 + c, f);
            if (which == 0) {
                sP[1][r][c] = ldf(pre_w, pbase1 + (size_t)(k0 + r) * 256 + m0 + c, f);
                sG[1][r][c] = ldf(gcn_w, gbase1 + (size_t)(m0 + r) * 256 + n0 + c, f);
            }
        }
        __syncthreads();
#pragma unroll 2
        for (int m = 0; m < 64; ++m) {
            float4 gv0 = *(const float4*)&sG[0][m][tn * 4];
            float av0[4];
#pragma unroll
            for (int a = 0; a < 4; ++a) av0[a] = sP[0][tk + 16 * a][m];
#pragma unroll
            for (int a = 0; a < 4; ++a) {
                acc0[a][0] += av0[a] * gv0.x;
                acc0[a][1] += av0[a] * gv0.y;
                acc0[a][2] += av0[a] * gv0.z;
                acc0[a][3] += av0[a] * gv0.w;
            }
            if (which == 0) {
                float4 gv1 = *(const float4*)&sG[1][m][tn * 4];
                float av1[4];
#pragma unroll
                for (int a = 0; a < 4; ++a) av1[a] = sP[1][tk + 16 * a][m];
#pragma unroll
                for (int a = 0; a < 4; ++a) {
                    acc1[a][0] += av1[a] * gv1.x;
                    acc1[a][1] += av1[a] * gv1.y;
                    acc1[a][2] += av1[a] * gv1.z;
                    acc1[a][3] += av1[a] * gv1.w;
                }
            }
        }
    }
#pragma unroll
    for (int a = 0; a < 4; ++a) {
        int k = k0 + tk + 16 * a;
#pragma unroll
        for (int b = 0; b < 4; ++b) {
            int n = n0 + tn * 4 + b;
            if (which == 0)      Wt0[(size_t)n * 256 + k]       = f2bf(2.f * acc0[a][b] + acc1[a][b]);
            else if (which == 1) Wt1[(size_t)n * 512 + k]       = f2bf(2.f * acc0[a][b]);
            else                 Wt1[(size_t)n * 512 + 256 + k] = f2bf(acc0[a][b]);
        }
    }
}

__global__ void k_prepb(const void* __restrict__ pre_b, const void* __restrict__ gcn_w,
                        const void* __restrict__ gcn_b,
                        float* __restrict__ cvec, float* __restrict__ dvec,
                        const int* __restrict__ flags) {
    int l = blockIdx.x, n = threadIdx.x;
    int f = flags[0];
    size_t pb0 = (size_t)(l * 2 + 0) * 256;
    size_t pb1 = (size_t)(l * 2 + 1) * 256;
    size_t g0 = (size_t)(l * 2 + 0) * 256 * 256;
    size_t g1 = (size_t)(l * 2 + 1) * 256 * 256;
    float a = 0.f, b = 0.f;
#pragma unroll 4
    for (int m = 0; m < 256; ++m) {
        a += ldf(pre_b, pb0 + m, f) * ldf(gcn_w, g0 + (size_t)m * 256 + n, f);
        b += ldf(pre_b, pb1 + m, f) * ldf(gcn_w, g1 + (size_t)m * 256 + n, f);
    }
    cvec[l * 256 + n] = 2.f * a + b;
    dvec[l * 256 + n] = 2.f * ldf(gcn_b, (size_t)(l * 2 + 0) * 256 + n, f)
                            + ldf(gcn_b, (size_t)(l * 2 + 1) * 256 + n, f);
}

// ---------------- main GEMM: out[i,:] = dinv[i] * (A[i,:] @ W + c) ----------------
// A row: k<256 from Xb (bf16), k>=256 from Yb (bf16). Wt is [256 x K] bf16 (W^T).
// 128x128 tile, BK=64, 4 waves (2x2), XOR-swizzled LDS.
__global__ __launch_bounds__(256)
void k_gemm(const unsigned short* __restrict__ Xb, const unsigned short* __restrict__ Yb,
            const unsigned short* __restrict__ Wt, const float* __restrict__ cvec,
            const float* __restrict__ dinv, unsigned short* __restrict__ out,
            int M, int K) {
    __shared__ unsigned short lds[2 * 128 * 64];  // A tile + W tile, 16KB each
    char* ldsb = (char*)lds;
    const int tid = threadIdx.x;
    const int lane = tid & 63;
    const int wid = tid >> 6;
    const int wm = wid >> 1, wn = wid & 1;
    const int row0 = blockIdx.x * 128;
    const int bn = blockIdx.y;

    f32x4 acc[4][4] = {};
    const int KT = K / 64;
    for (int kt = 0; kt < KT; ++kt) {
        const int k0 = kt * 64;
        const unsigned short* Asrc = (k0 < 256) ? Xb : Yb;
        const int ak0 = (k0 < 256) ? k0 : k0 - 256;
        int4 ra[4], rw[4];
#pragma unroll
        for (int q = 0; q < 4; ++q) {
            int id = q * 256 + tid;        // 0..1023 chunks of 16B (8 bf16)
            int r = id >> 3;               // tile row 0..127
            int cb = id & 7;               // chunk in row
            int grow = row0 + r; if (grow > M - 1) grow = M - 1;
            ra[q] = *(const int4*)(Asrc + (size_t)grow * 256 + ak0 + cb * 8);
            rw[q] = *(const int4*)(Wt + (size_t)(bn * 128 + r) * K + k0 + cb * 8);
        }
        __syncthreads();   // prior LDS reads done
#pragma unroll
        for (int q = 0; q < 4; ++q) {
            int id = q * 256 + tid;
            int r = id >> 3, cb = id & 7;
            int sw = (cb * 16) ^ ((r & 7) << 4);
            *(int4*)(ldsb + r * 128 + sw) = ra[q];
            *(int4*)(ldsb + 16384 + r * 128 + sw) = rw[q];
        }
        __syncthreads();
#pragma unroll
        for (int kk = 0; kk < 2; ++kk) {
            bf16x8 af[4], bfr[4];
            int byte = kk * 64 + ((lane >> 4) << 4);
#pragma unroll
            for (int m = 0; m < 4; ++m) {
                int r = wm * 64 + m * 16 + (lane & 15);
                af[m] = *(const bf16x8*)(ldsb + r * 128 + (byte ^ ((r & 7) << 4)));
            }
#pragma unroll
            for (int n = 0; n < 4; ++n) {
                int r = wn * 64 + n * 16 + (lane & 15);
                bfr[n] = *(const bf16x8*)(ldsb + 16384 + r * 128 + (byte ^ ((r & 7) << 4)));
            }
#pragma unroll
            for (int m = 0; m < 4; ++m)
#pragma unroll
                for (int n = 0; n < 4; ++n)
                    acc[m][n] = __builtin_amdgcn_mfma_f32_16x16x32_bf16(af[m], bfr[n], acc[m][n], 0, 0, 0);
        }
    }
    // epilogue: val = (acc + c[col]) * dinv[row], bf16 store
#pragma unroll
    for (int m = 0; m < 4; ++m) {
#pragma unroll
        for (int j = 0; j < 4; ++j) {
            int rt = wm * 64 + m * 16 + ((lane >> 4) << 2) + j;
            int grow = row0 + rt;
            if (grow < M) {
                float di = dinv[grow];
#pragma unroll
                for (int n = 0; n < 4; ++n) {
                    int colc = bn * 128 + wn * 64 + n * 16 + (lane & 15);
                    float v = (acc[m][n][j] + cvec[colc]) * di;
                    out[(size_t)grow * 256 + colc] = f2bf(v);
                }
            }
        }
    }
}

// ---------------- aggregation: Y[i] = dinv[i]*(U[i] + sum_{j in in(i)} U[j]) + d ----------------
// wave = one node; 16-deep gather MLP, then 4-deep, then scalar tail.
__global__ __launch_bounds__(256)
void k_agg(const unsigned short* __restrict__ U, const int* __restrict__ rowptr,
           const int* __restrict__ col, const float* __restrict__ dinv,
           const float* __restrict__ dvec, unsigned short* __restrict__ Y, int N) {
    int w = (blockIdx.x * 256 + threadIdx.x) >> 6;   // node per wave
    int lane = threadIdx.x & 63;
    if (w >= N) return;
    const size_t loff = (size_t)lane * 4;
    ushort4 sv = *(const ushort4*)(U + (size_t)w * 256 + loff);
    float a0 = bf2f(sv.x), a1 = bf2f(sv.y), a2 = bf2f(sv.z), a3 = bf2f(sv.w);
    int beg = rowptr[w], end = rowptr[w + 1];
    int e = beg;
    for (; e + 16 <= end; e += 16) {
        int s[16];
        ushort4 v[16];
#pragma unroll
        for (int u = 0; u < 16; ++u) s[u] = __builtin_amdgcn_readfirstlane(col[e + u]);
#pragma unroll
        for (int u = 0; u < 16; ++u) v[u] = *(const ushort4*)(U + (size_t)s[u] * 256 + loff);
#pragma unroll
        for (int u = 0; u < 16; ++u) {
            a0 += bf2f(v[u].x); a1 += bf2f(v[u].y);
            a2 += bf2f(v[u].z); a3 += bf2f(v[u].w);
        }
    }
    for (; e + 4 <= end; e += 4) {
        int s[4];
        ushort4 v[4];
#pragma unroll
        for (int u = 0; u < 4; ++u) s[u] = __builtin_amdgcn_readfirstlane(col[e + u]);
#pragma unroll
        for (int u = 0; u < 4; ++u) v[u] = *(const ushort4*)(U + (size_t)s[u] * 256 + loff);
#pragma unroll
        for (int u = 0; u < 4; ++u) {
            a0 += bf2f(v[u].x); a1 += bf2f(v[u].y);
            a2 += bf2f(v[u].z); a3 += bf2f(v[u].w);
        }
    }
    for (; e < end; ++e) {
        int s = __builtin_amdgcn_readfirstlane(col[e]);
        ushort4 v = *(const ushort4*)(U + (size_t)s * 256 + loff);
        a0 += bf2f(v.x); a1 += bf2f(v.y); a2 += bf2f(v.z); a3 += bf2f(v.w);
    }
    float di = dinv[w];
    int f = lane * 4;
    a0 = a0 * di + dvec[f + 0];
    a1 = a1 * di + dvec[f + 1];
    a2 = a2 * di + dvec[f + 2];
    a3 = a3 * di + dvec[f + 3];
    ushort4 o; o.x = f2bf(a0); o.y = f2bf(a1); o.z = f2bf(a2); o.w = f2bf(a3);
    *(ushort4*)(Y + (size_t)w * 256 + loff) = o;
}

// ---------------- pooling (batch is sorted) ----------------
__global__ __launch_bounds__(256)
void k_pool(const unsigned short* __restrict__ Y, const int* __restrict__ batch, int N,
            float* __restrict__ psum, unsigned int* __restrict__ pkey, int* __restrict__ pcnt,
            const int* __restrict__ flags) {
    int f = threadIdx.x;
    int base = blockIdx.x * 64;
    if (base >= N) return;
    int i64 = flags[1];
    int g0 = ldi(batch, base, i64); int curg = g0 < 0 ? 0 : (g0 > 63 ? 63 : g0);
    float s = 0.f, mx = -__builtin_inff(); int cnt = 0;
#pragma unroll 4
    for (int r = 0; r < 64; ++r) {
        int node = base + r;
        if (node >= N) break;
        int g = ldi(batch, node, i64); g = g < 0 ? 0 : (g > 63 ? 63 : g);
        if (g != curg) {
            atomicAdd(&psum[curg * 256 + f], s);
            atomicMax(&pkey[curg * 256 + f], fenc(mx));
            if (f == 0) atomicAdd(&pcnt[curg], cnt);
            curg = g; s = 0.f; mx = -__builtin_inff(); cnt = 0;
        }
        float v = bf2f(Y[(size_t)node * 256 + f]);
        s += v; mx = fmaxf(mx, v); ++cnt;
    }
    atomicAdd(&psum[curg * 256 + f], s);
    atomicMax(&pkey[curg * 256 + f], fenc(mx));
    if (f == 0) atomicAdd(&pcnt[curg], cnt);
}

// ---------------- classifier ----------------
__global__ __launch_bounds__(64)
void k_cls(const float* __restrict__ psum, const unsigned int* __restrict__ pkey,
           const int* __restrict__ pcnt, const void* __restrict__ clsw,
           const void* __restrict__ clsb, float* __restrict__ outf,
           unsigned short* __restrict__ outu, const int* __restrict__ flags) {
    __shared__ float pooled[256];
    int g = blockIdx.x, c = threadIdx.x;
    int f = flags[0];
    int cnt = pcnt[g];
    for (int m = c; m < 256; m += 64) {
        float mean = psum[g * 256 + m] / (float)(cnt > 0 ? cnt : 1);
        float mx = (cnt > 0) ? fdec(pkey[g * 256 + m]) : 0.f;
        pooled[m] = mean + mx;
    }
    __syncthreads();
    float a = ldf(clsb, c, f);
#pragma unroll 8
    for (int m = 0; m < 256; ++m) a += pooled[m] * ldf(clsw, (size_t)m * 64 + c, f);
    if (f) outf[g * 64 + c] = a;
    else   outu[g * 64 + c] = f2bf(a);
}

extern "C" void kernel_launch(void* const* d_in, const int* in_sizes, int n_in,
                              void* d_out, int out_size, void* d_ws, size_t ws_size,
                              hipStream_t stream) {
    const void*           X     = d_in[0];
    const int*            EI    = (const int*)d_in[1];
    const int*            BATCH = (const int*)d_in[3];
    const void*           PREW  = d_in[4];
    const void*           PREB  = d_in[5];
    const void*           GCNW  = d_in[6];
    const void*           GCNB  = d_in[7];
    const void*           CLSW  = d_in[8];
    const void*           CLSB  = d_in[9];

    const int N = in_sizes[3];
    const int E = in_sizes[1] / 2;

    char* ws = (char*)d_ws;
    size_t off = 0;
    auto alloc = [&](size_t b) { size_t o = off; off += (b + 255) & ~(size_t)255; return o; };
    int*            flags  = (int*)(ws + alloc(256));
    float*          dinv   = (float*)(ws + alloc((size_t)N * 4));
    int*            hist   = (int*)(ws + alloc((size_t)N * 4));
    int*            cursor = (int*)(ws + alloc((size_t)N * 4));
    int*            rowptr = (int*)(ws + alloc((size_t)(N + 1) * 4));
    int*            col    = (int*)(ws + alloc((size_t)E * 4));
    unsigned short* Wt0    = (unsigned short*)(ws + alloc(256 * 256 * 2));
    unsigned short* Wt1    = (unsigned short*)(ws + alloc(256 * 512 * 2));
    float*          cvec   = (float*)(ws + alloc(512 * 4));
    float*          dvec   = (float*)(ws + alloc(512 * 4));
    float*          psum   = (float*)(ws + alloc(64 * 256 * 4));
    unsigned int*   pkey   = (unsigned int*)(ws + alloc(64 * 256 * 4));
    int*            pcnt   = (int*)(ws + alloc(64 * 4));
    unsigned short* Xb     = (unsigned short*)(ws + alloc((size_t)N * 256 * 2));
    unsigned short* U      = (unsigned short*)(ws + alloc((size_t)N * 256 * 2));
    unsigned short* Y      = (unsigned short*)(ws + alloc((size_t)N * 256 * 2));

    int zt = 2 * N + 32768 + 64;
    k_zero<<<(zt + 255) / 256, 256, 0, stream>>>(hist, cursor, psum, pkey, pcnt, N);

    int xstride = (in_sizes[0] / 2) / 1024; if (xstride < 1) xstride = 1;
    int estride = E / 1024;                 if (estride < 1) estride = 1;
    k_detect<<<1, 256, 0, stream>>>((const unsigned short*)X, xstride, EI, estride, flags);

    size_t xelem = (size_t)N * 256;
    k_cvt<<<(int)((xelem / 8 + 255) / 256), 256, 0, stream>>>(X, Xb, xelem, flags);

    k_hist<<<(E + 255) / 256, 256, 0, stream>>>(EI, E, N, hist, flags);
    k_dinv<<<(N + 255) / 256, 256, 0, stream>>>(hist, dinv, N);
    k_scan<<<1, 1024, 0, stream>>>(hist, rowptr, N);
    k_scatter<<<(E + 255) / 256, 256, 0, stream>>>(EI, E, N, rowptr, cursor, col, flags);
    k_prepw<<<dim3(16, 3), 256, 0, stream>>>(PREW, GCNW, Wt0, Wt1, flags);
    k_prepb<<<2, 256, 0, stream>>>(PREB, GCNW, GCNB, cvec, dvec, flags);

    dim3 ggrid((N + 127) / 128, 2);
    k_gemm<<<ggrid, 256, 0, stream>>>(Xb, U, Wt0, cvec, dinv, U, N, 256);
    k_agg<<<(N + 3) / 4, 256, 0, stream>>>(U, rowptr, col, dinv, dvec, Y, N);
    k_gemm<<<ggrid, 256, 0, stream>>>(Xb, Y, Wt1, cvec + 256, dinv, U, N, 512);
    k_agg<<<(N + 3) / 4, 256, 0, stream>>>(U, rowptr, col, dinv, dvec + 256, Y, N);
    k_pool<<<(N + 63) / 64, 256, 0, stream>>>(Y, BATCH, N, psum, pkey, pcnt, flags);
    k_cls<<<64, 64, 0, stream>>>(psum, pkey, pcnt, CLSW, CLSB,
                                 (float*)d_out, (unsigned short*)d_out, flags);
}

// Round 5
// 518.522 us; speedup vs baseline: 1.1825x; 1.1825x over previous
//
#include <hip/hip_runtime.h>

typedef __attribute__((ext_vector_type(8))) short bf16x8;
typedef __attribute__((ext_vector_type(4))) float f32x4;

__device__ inline float bf2f(unsigned short u) {
    union { float f; unsigned int i; } v; v.i = ((unsigned int)u) << 16; return v.f;
}
__device__ inline unsigned short f2bf(float f) {
    union { float f; unsigned int u; } v; v.f = f;
    unsigned int x = v.u;
    unsigned int r = x + 0x7FFFu + ((x >> 16) & 1u);
    return (unsigned short)(r >> 16);
}
// order-preserving float <-> uint for atomicMax
__device__ inline unsigned int fenc(float x) {
    union { float f; unsigned int u; } v; v.f = x;
    return (v.u & 0x80000000u) ? ~v.u : (v.u | 0x80000000u);
}
__device__ inline float fdec(unsigned int k) {
    union { float f; unsigned int u; } v;
    v.u = (k & 0x80000000u) ? (k & 0x7FFFFFFFu) : ~k;
    return v.f;
}
// dual-format loads: f32flag ? float32 buffer : bf16 buffer
__device__ inline float ldf(const void* p, size_t i, int f32) {
    return f32 ? ((const float*)p)[i] : bf2f(((const unsigned short*)p)[i]);
}
// i64flag ? int64 buffer (values < 2^31, take low word) : int32 buffer
__device__ inline int ldi(const int* p, size_t i, int i64) {
    return i64 ? p[2 * i] : p[i];
}

// ---------------- format detection (device-side, deterministic) ----------------
__global__ __launch_bounds__(256)
void k_detect(const unsigned short* __restrict__ xu, int xstride,
              const int* __restrict__ ei, int estride, int* __restrict__ flags) {
    __shared__ int cnt, orv;
    if (threadIdx.x == 0) { cnt = 0; orv = 0; }
    __syncthreads();
    int c = 0, o = 0;
    for (int s = 0; s < 4; ++s) {
        int j = threadIdx.x * 4 + s;               // 0..1023
        size_t k = (size_t)j * xstride;            // < xelems/2
        unsigned short u = xu[2 * k];              // even ushort
        int e = (u >> 7) & 0xFF;
        if (e >= 100 && e <= 140) ++c;             // sane bf16 exponent?
        size_t idx = (size_t)j * estride;          // < E
        o |= ei[2 * idx + 1];                      // odd word
    }
    atomicAdd(&cnt, c); atomicOr(&orv, o);
    __syncthreads();
    if (threadIdx.x == 0) {
        flags[0] = (cnt < 768) ? 1 : 0;   // 1 => floats are f32
        flags[1] = (orv == 0) ? 1 : 0;    // 1 => ints are int64
    }
}

// ---------------- zero scratch ----------------
__global__ void k_zero(int* __restrict__ hist, int* __restrict__ cursor,
                       float* __restrict__ psum, unsigned int* __restrict__ pkey,
                       int* __restrict__ pcnt, int N) {
    int t = blockIdx.x * 256 + threadIdx.x;
    if (t < N) hist[t] = 0;
    else if (t < 2 * N) cursor[t - N] = 0;
    else if (t < 2 * N + 16384) psum[t - 2 * N] = 0.f;
    else if (t < 2 * N + 32768) pkey[t - 2 * N - 16384] = 0u;
    else if (t < 2 * N + 32768 + 64) pcnt[t - 2 * N - 32768] = 0;
}

// ---------------- X -> bf16 conversion (or copy if already bf16) ----------------
__global__ __launch_bounds__(256)
void k_cvt(const void* __restrict__ X, unsigned short* __restrict__ Xb,
           size_t nelem, const int* __restrict__ flags) {
    int f = flags[0];
    size_t i = ((size_t)blockIdx.x * 256 + threadIdx.x) * 8;
    if (i >= nelem) return;
    if (f) {
        const float* s = (const float*)X + i;
        float4 f0 = *(const float4*)s;
        float4 f1 = *(const float4*)(s + 4);
        int4 o;
        o.x = (int)f2bf(f0.x) | ((int)f2bf(f0.y) << 16);
        o.y = (int)f2bf(f0.z) | ((int)f2bf(f0.w) << 16);
        o.z = (int)f2bf(f1.x) | ((int)f2bf(f1.y) << 16);
        o.w = (int)f2bf(f1.z) | ((int)f2bf(f1.w) << 16);
        *(int4*)(Xb + i) = o;
    } else {
        *(int4*)(Xb + i) = *(const int4*)((const unsigned short*)X + i);
    }
}

// ---------------- weight convert + transpose ----------------
// Pb[i][k][m] = bf16(pre_w[i][k][m])      (straight convert)
// Gt[i][n][m] = bf16(gcn_w[i][m][n])      (transpose via padded LDS tile)
// grid (16, 4): 4 products x 16 64x64 tiles, 256 thr.
__global__ __launch_bounds__(256)
void k_cvtw(const void* __restrict__ pre_w, const void* __restrict__ gcn_w,
            unsigned short* __restrict__ Pb, unsigned short* __restrict__ Gt,
            const int* __restrict__ flags) {
    __shared__ float tile[64][65];
    const int i = blockIdx.y;
    const int m0 = (blockIdx.x & 3) * 64;
    const int n0 = (blockIdx.x >> 2) * 64;
    const int f = flags[0];
    const size_t base = (size_t)i * 65536;
#pragma unroll
    for (int q = 0; q < 16; ++q) {
        int idx = q * 256 + threadIdx.x;
        int r = idx >> 6, c = idx & 63;
        size_t src = base + (size_t)(m0 + r) * 256 + n0 + c;
        Pb[src] = f2bf(ldf(pre_w, src, f));
        tile[r][c] = ldf(gcn_w, src, f);
    }
    __syncthreads();
#pragma unroll
    for (int q = 0; q < 16; ++q) {
        int idx = q * 256 + threadIdx.x;
        int r = idx >> 6, c = idx & 63;
        Gt[base + (size_t)(n0 + r) * 256 + m0 + c] = f2bf(tile[c][r]);
    }
}

// ---------------- weight folding via MFMA ----------------
// Q^T[n][k] = sum_m Gt[n][m] * P[k][m]   (A = Gt rows, B = P rows, both contiguous)
// which=0: Wt0[n*256+k]     = 2*Q0^T + Q1^T
// which=1: Wt1[n*512+k]     = 2*Q2^T
// which=2: Wt1[n*512+256+k] =   Q3^T
// grid (64, 3), 256 thr = 4 waves; each wave one 16(n) x 16(k) tile, K=256.
__global__ __launch_bounds__(256)
void k_prepw(const unsigned short* __restrict__ Pb, const unsigned short* __restrict__ Gt,
             unsigned short* __restrict__ Wt0, unsigned short* __restrict__ Wt1) {
    const int which = blockIdx.y;
    const int wid = threadIdx.x >> 6, lane = threadIdx.x & 63;
    const int tile = blockIdx.x * 4 + wid;       // 0..255
    const int n0 = (tile >> 4) * 16, k0 = (tile & 15) * 16;
    const int l15 = lane & 15, hi = lane >> 4;
    size_t base0, base1 = 0;
    if (which == 0)      { base0 = 0; base1 = 65536; }
    else if (which == 1) { base0 = 2 * 65536; }
    else                 { base0 = 3 * 65536; }
    f32x4 acc0 = {}, acc1 = {};
    const unsigned short* ga = Gt + base0 + (size_t)(n0 + l15) * 256 + hi * 8;
    const unsigned short* pa = Pb + base0 + (size_t)(k0 + l15) * 256 + hi * 8;
    const unsigned short* gb = Gt + base1 + (size_t)(n0 + l15) * 256 + hi * 8;
    const unsigned short* pb = Pb + base1 + (size_t)(k0 + l15) * 256 + hi * 8;
#pragma unroll
    for (int kt = 0; kt < 8; ++kt) {
        bf16x8 a0 = *(const bf16x8*)(ga + kt * 32);
        bf16x8 b0 = *(const bf16x8*)(pa + kt * 32);
        acc0 = __builtin_amdgcn_mfma_f32_16x16x32_bf16(a0, b0, acc0, 0, 0, 0);
        if (which == 0) {
            bf16x8 a1 = *(const bf16x8*)(gb + kt * 32);
            bf16x8 b1 = *(const bf16x8*)(pb + kt * 32);
            acc1 = __builtin_amdgcn_mfma_f32_16x16x32_bf16(a1, b1, acc1, 0, 0, 0);
        }
    }
#pragma unroll
    for (int j = 0; j < 4; ++j) {
        int n = n0 + hi * 4 + j;
        int k = k0 + l15;
        if (which == 0)      Wt0[(size_t)n * 256 + k]       = f2bf(2.f * acc0[j] + acc1[j]);
        else if (which == 1) Wt1[(size_t)n * 512 + k]       = f2bf(2.f * acc0[j]);
        else                 Wt1[(size_t)n * 512 + 256 + k] = f2bf(acc0[j]);
    }
}

// ---------------- bias folding (uses Gt: contiguous bf16 rows) ----------------
__global__ __launch_bounds__(256)
void k_prepb(const void* __restrict__ pre_b, const unsigned short* __restrict__ Gt,
             const void* __restrict__ gcn_b,
             float* __restrict__ cvec, float* __restrict__ dvec,
             const int* __restrict__ flags) {
    __shared__ float pb[2][256];
    const int l = blockIdx.x, n = threadIdx.x;
    const int f = flags[0];
    pb[0][n] = ldf(pre_b, (size_t)(l * 2 + 0) * 256 + n, f);
    pb[1][n] = ldf(pre_b, (size_t)(l * 2 + 1) * 256 + n, f);
    __syncthreads();
    const unsigned short* g0 = Gt + (size_t)(l * 2 + 0) * 65536 + (size_t)n * 256;
    const unsigned short* g1 = Gt + (size_t)(l * 2 + 1) * 65536 + (size_t)n * 256;
    float a = 0.f, b = 0.f;
#pragma unroll 4
    for (int mc = 0; mc < 32; ++mc) {
        bf16x8 v0 = *(const bf16x8*)(g0 + mc * 8);
        bf16x8 v1 = *(const bf16x8*)(g1 + mc * 8);
#pragma unroll
        for (int u = 0; u < 8; ++u) {
            a += pb[0][mc * 8 + u] * bf2f((unsigned short)v0[u]);
            b += pb[1][mc * 8 + u] * bf2f((unsigned short)v1[u]);
        }
    }
    cvec[l * 256 + n] = 2.f * a + b;
    dvec[l * 256 + n] = 2.f * ldf(gcn_b, (size_t)(l * 2 + 0) * 256 + n, f)
                            + ldf(gcn_b, (size_t)(l * 2 + 1) * 256 + n, f);
}

// ---------------- CSR build ----------------
__global__ void k_hist(const int* __restrict__ ei, int E, int N,
                       int* __restrict__ hist, const int* __restrict__ flags) {
    int e = blockIdx.x * 256 + threadIdx.x;
    if (e >= E) return;
    int i64 = flags[1];
    int d = ldi(ei, (size_t)E + e, i64); d = d < 0 ? 0 : (d >= N ? N - 1 : d);
    atomicAdd(&hist[d], 1);
}

__global__ __launch_bounds__(1024)
void k_scan(const int* __restrict__ hist, int* __restrict__ rowptr,
            float* __restrict__ dinv, int N) {
    __shared__ int ssum[1024];
    int t = threadIdx.x;
    int chunk = (N + 1023) / 1024;
    int lo = t * chunk, hi = lo + chunk; if (hi > N) hi = N; if (lo > N) lo = N;
    int s = 0;
#pragma unroll 4
    for (int i = lo; i < hi; ++i) s += hist[i];
    ssum[t] = s;
    __syncthreads();
    for (int off = 1; off < 1024; off <<= 1) {
        int v = (t >= off) ? ssum[t - off] : 0;
        __syncthreads();
        ssum[t] += v;
        __syncthreads();
    }
    int run = ssum[t] - s;
    for (int i = lo; i < hi; ++i) {
        int h = hist[i];
        rowptr[i] = run; run += h;
        dinv[i] = rsqrtf((float)(h + 1));
    }
    if (t == 1023) rowptr[N] = ssum[1023];
}

__global__ void k_scatter(const int* __restrict__ ei, int E, int N,
                          const int* __restrict__ rowptr, int* __restrict__ cursor,
                          int* __restrict__ col, const int* __restrict__ flags) {
    int e = blockIdx.x * 256 + threadIdx.x;
    if (e >= E) return;
    int i64 = flags[1];
    int s = ldi(ei, (size_t)e, i64);     s = s < 0 ? 0 : (s >= N ? N - 1 : s);
    int d = ldi(ei, (size_t)E + e, i64); d = d < 0 ? 0 : (d >= N ? N - 1 : d);
    int pos = rowptr[d] + atomicAdd(&cursor[d], 1);
    col[pos] = s;
}

// ---------------- main GEMM: out[i,:] = dinv[i] * (A[i,:] @ W + c) ----------------
// A row: k<256 from Xb (bf16), k>=256 from Yb (bf16). Wt is [256 x K] bf16 (W^T).
// 128x128 tile, BK=64, 4 waves (2x2), XOR-swizzled LDS.
__global__ __launch_bounds__(256)
void k_gemm(const unsigned short* __restrict__ Xb, const unsigned short* __restrict__ Yb,
            const unsigned short* __restrict__ Wt, const float* __restrict__ cvec,
            const float* __restrict__ dinv, unsigned short* __restrict__ out,
            int M, int K) {
    __shared__ unsigned short lds[2 * 128 * 64];  // A tile + W tile, 16KB each
    char* ldsb = (char*)lds;
    const int tid = threadIdx.x;
    const int lane = tid & 63;
    const int wid = tid >> 6;
    const int wm = wid >> 1, wn = wid & 1;
    const int row0 = blockIdx.x * 128;
    const int bn = blockIdx.y;

    f32x4 acc[4][4] = {};
    const int KT = K / 64;
    for (int kt = 0; kt < KT; ++kt) {
        const int k0 = kt * 64;
        const unsigned short* Asrc = (k0 < 256) ? Xb : Yb;
        const int ak0 = (k0 < 256) ? k0 : k0 - 256;
        int4 ra[4], rw[4];
#pragma unroll
        for (int q = 0; q < 4; ++q) {
            int id = q * 256 + tid;        // 0..1023 chunks of 16B (8 bf16)
            int r = id >> 3;               // tile row 0..127
            int cb = id & 7;               // chunk in row
            int grow = row0 + r; if (grow > M - 1) grow = M - 1;
            ra[q] = *(const int4*)(Asrc + (size_t)grow * 256 + ak0 + cb * 8);
            rw[q] = *(const int4*)(Wt + (size_t)(bn * 128 + r) * K + k0 + cb * 8);
        }
        __syncthreads();   // prior LDS reads done
#pragma unroll
        for (int q = 0; q < 4; ++q) {
            int id = q * 256 + tid;
            int r = id >> 3, cb = id & 7;
            int sw = (cb * 16) ^ ((r & 7) << 4);
            *(int4*)(ldsb + r * 128 + sw) = ra[q];
            *(int4*)(ldsb + 16384 + r * 128 + sw) = rw[q];
        }
        __syncthreads();
#pragma unroll
        for (int kk = 0; kk < 2; ++kk) {
            bf16x8 af[4], bfr[4];
            int byte = kk * 64 + ((lane >> 4) << 4);
#pragma unroll
            for (int m = 0; m < 4; ++m) {
                int r = wm * 64 + m * 16 + (lane & 15);
                af[m] = *(const bf16x8*)(ldsb + r * 128 + (byte ^ ((r & 7) << 4)));
            }
#pragma unroll
            for (int n = 0; n < 4; ++n) {
                int r = wn * 64 + n * 16 + (lane & 15);
                bfr[n] = *(const bf16x8*)(ldsb + 16384 + r * 128 + (byte ^ ((r & 7) << 4)));
            }
#pragma unroll
            for (int m = 0; m < 4; ++m)
#pragma unroll
                for (int n = 0; n < 4; ++n)
                    acc[m][n] = __builtin_amdgcn_mfma_f32_16x16x32_bf16(af[m], bfr[n], acc[m][n], 0, 0, 0);
        }
    }
    // epilogue: val = (acc + c[col]) * dinv[row], bf16 store
#pragma unroll
    for (int m = 0; m < 4; ++m) {
#pragma unroll
        for (int j = 0; j < 4; ++j) {
            int rt = wm * 64 + m * 16 + ((lane >> 4) << 2) + j;
            int grow = row0 + rt;
            if (grow < M) {
                float di = dinv[grow];
#pragma unroll
                for (int n = 0; n < 4; ++n) {
                    int colc = bn * 128 + wn * 64 + n * 16 + (lane & 15);
                    float v = (acc[m][n][j] + cvec[colc]) * di;
                    out[(size_t)grow * 256 + colc] = f2bf(v);
                }
            }
        }
    }
}

// ---------------- aggregation: Y[i] = dinv[i]*(U[i] + sum_{j in in(i)} U[j]) + d ----------------
// wave = one node; 16-deep gather MLP, then 4-deep, then scalar tail.
__global__ __launch_bounds__(256)
void k_agg(const unsigned short* __restrict__ U, const int* __restrict__ rowptr,
           const int* __restrict__ col, const float* __restrict__ dinv,
           const float* __restrict__ dvec, unsigned short* __restrict__ Y, int N) {
    int w = (blockIdx.x * 256 + threadIdx.x) >> 6;   // node per wave
    int lane = threadIdx.x & 63;
    if (w >= N) return;
    const size_t loff = (size_t)lane * 4;
    ushort4 sv = *(const ushort4*)(U + (size_t)w * 256 + loff);
    float a0 = bf2f(sv.x), a1 = bf2f(sv.y), a2 = bf2f(sv.z), a3 = bf2f(sv.w);
    int beg = rowptr[w], end = rowptr[w + 1];
    int e = beg;
    for (; e + 16 <= end; e += 16) {
        int s[16];
        ushort4 v[16];
#pragma unroll
        for (int u = 0; u < 16; ++u) s[u] = __builtin_amdgcn_readfirstlane(col[e + u]);
#pragma unroll
        for (int u = 0; u < 16; ++u) v[u] = *(const ushort4*)(U + (size_t)s[u] * 256 + loff);
#pragma unroll
        for (int u = 0; u < 16; ++u) {
            a0 += bf2f(v[u].x); a1 += bf2f(v[u].y);
            a2 += bf2f(v[u].z); a3 += bf2f(v[u].w);
        }
    }
    for (; e + 4 <= end; e += 4) {
        int s[4];
        ushort4 v[4];
#pragma unroll
        for (int u = 0; u < 4; ++u) s[u] = __builtin_amdgcn_readfirstlane(col[e + u]);
#pragma unroll
        for (int u = 0; u < 4; ++u) v[u] = *(const ushort4*)(U + (size_t)s[u] * 256 + loff);
#pragma unroll
        for (int u = 0; u < 4; ++u) {
            a0 += bf2f(v[u].x); a1 += bf2f(v[u].y);
            a2 += bf2f(v[u].z); a3 += bf2f(v[u].w);
        }
    }
    for (; e < end; ++e) {
        int s = __builtin_amdgcn_readfirstlane(col[e]);
        ushort4 v = *(const ushort4*)(U + (size_t)s * 256 + loff);
        a0 += bf2f(v.x); a1 += bf2f(v.y); a2 += bf2f(v.z); a3 += bf2f(v.w);
    }
    float di = dinv[w];
    int f = lane * 4;
    a0 = a0 * di + dvec[f + 0];
    a1 = a1 * di + dvec[f + 1];
    a2 = a2 * di + dvec[f + 2];
    a3 = a3 * di + dvec[f + 3];
    ushort4 o; o.x = f2bf(a0); o.y = f2bf(a1); o.z = f2bf(a2); o.w = f2bf(a3);
    *(ushort4*)(Y + (size_t)w * 256 + loff) = o;
}

// ---------------- pooling (batch is sorted) ----------------
__global__ __launch_bounds__(256)
void k_pool(const unsigned short* __restrict__ Y, const int* __restrict__ batch, int N,
            float* __restrict__ psum, unsigned int* __restrict__ pkey, int* __restrict__ pcnt,
            const int* __restrict__ flags) {
    int f = threadIdx.x;
    int base = blockIdx.x * 64;
    if (base >= N) return;
    int i64 = flags[1];
    int g0 = ldi(batch, base, i64); int curg = g0 < 0 ? 0 : (g0 > 63 ? 63 : g0);
    float s = 0.f, mx = -__builtin_inff(); int cnt = 0;
#pragma unroll 4
    for (int r = 0; r < 64; ++r) {
        int node = base + r;
        if (node >= N) break;
        int g = ldi(batch, node, i64); g = g < 0 ? 0 : (g > 63 ? 63 : g);
        if (g != curg) {
            atomicAdd(&psum[curg * 256 + f], s);
            atomicMax(&pkey[curg * 256 + f], fenc(mx));
            if (f == 0) atomicAdd(&pcnt[curg], cnt);
            curg = g; s = 0.f; mx = -__builtin_inff(); cnt = 0;
        }
        float v = bf2f(Y[(size_t)node * 256 + f]);
        s += v; mx = fmaxf(mx, v); ++cnt;
    }
    atomicAdd(&psum[curg * 256 + f], s);
    atomicMax(&pkey[curg * 256 + f], fenc(mx));
    if (f == 0) atomicAdd(&pcnt[curg], cnt);
}

// ---------------- classifier ----------------
__global__ __launch_bounds__(64)
void k_cls(const float* __restrict__ psum, const unsigned int* __restrict__ pkey,
           const int* __restrict__ pcnt, const void* __restrict__ clsw,
           const void* __restrict__ clsb, float* __restrict__ outf,
           unsigned short* __restrict__ outu, const int* __restrict__ flags) {
    __shared__ float pooled[256];
    int g = blockIdx.x, c = threadIdx.x;
    int f = flags[0];
    int cnt = pcnt[g];
    for (int m = c; m < 256; m += 64) {
        float mean = psum[g * 256 + m] / (float)(cnt > 0 ? cnt : 1);
        float mx = (cnt > 0) ? fdec(pkey[g * 256 + m]) : 0.f;
        pooled[m] = mean + mx;
    }
    __syncthreads();
    float a = ldf(clsb, c, f);
#pragma unroll 8
    for (int m = 0; m < 256; ++m) a += pooled[m] * ldf(clsw, (size_t)m * 64 + c, f);
    if (f) outf[g * 64 + c] = a;
    else   outu[g * 64 + c] = f2bf(a);
}

extern "C" void kernel_launch(void* const* d_in, const int* in_sizes, int n_in,
                              void* d_out, int out_size, void* d_ws, size_t ws_size,
                              hipStream_t stream) {
    const void*           X     = d_in[0];
    const int*            EI    = (const int*)d_in[1];
    const int*            BATCH = (const int*)d_in[3];
    const void*           PREW  = d_in[4];
    const void*           PREB  = d_in[5];
    const void*           GCNW  = d_in[6];
    const void*           GCNB  = d_in[7];
    const void*           CLSW  = d_in[8];
    const void*           CLSB  = d_in[9];

    const int N = in_sizes[3];
    const int E = in_sizes[1] / 2;

    char* ws = (char*)d_ws;
    size_t off = 0;
    auto alloc = [&](size_t b) { size_t o = off; off += (b + 255) & ~(size_t)255; return o; };
    int*            flags  = (int*)(ws + alloc(256));
    float*          dinv   = (float*)(ws + alloc((size_t)N * 4));
    int*            hist   = (int*)(ws + alloc((size_t)N * 4));
    int*            cursor = (int*)(ws + alloc((size_t)N * 4));
    int*            rowptr = (int*)(ws + alloc((size_t)(N + 1) * 4));
    int*            col    = (int*)(ws + alloc((size_t)E * 4));
    unsigned short* Pb     = (unsigned short*)(ws + alloc(4 * 65536 * 2));
    unsigned short* Gt     = (unsigned short*)(ws + alloc(4 * 65536 * 2));
    unsigned short* Wt0    = (unsigned short*)(ws + alloc(256 * 256 * 2));
    unsigned short* Wt1    = (unsigned short*)(ws + alloc(256 * 512 * 2));
    float*          cvec   = (float*)(ws + alloc(512 * 4));
    float*          dvec   = (float*)(ws + alloc(512 * 4));
    float*          psum   = (float*)(ws + alloc(64 * 256 * 4));
    unsigned int*   pkey   = (unsigned int*)(ws + alloc(64 * 256 * 4));
    int*            pcnt   = (int*)(ws + alloc(64 * 4));
    unsigned short* Xb     = (unsigned short*)(ws + alloc((size_t)N * 256 * 2));
    unsigned short* U      = (unsigned short*)(ws + alloc((size_t)N * 256 * 2));
    unsigned short* Y      = (unsigned short*)(ws + alloc((size_t)N * 256 * 2));

    int zt = 2 * N + 32768 + 64;
    k_zero<<<(zt + 255) / 256, 256, 0, stream>>>(hist, cursor, psum, pkey, pcnt, N);

    int xstride = (in_sizes[0] / 2) / 1024; if (xstride < 1) xstride = 1;
    int estride = E / 1024;                 if (estride < 1) estride = 1;
    k_detect<<<1, 256, 0, stream>>>((const unsigned short*)X, xstride, EI, estride, flags);

    size_t xelem = (size_t)N * 256;
    k_cvt<<<(int)((xelem / 8 + 255) / 256), 256, 0, stream>>>(X, Xb, xelem, flags);

    k_hist<<<(E + 255) / 256, 256, 0, stream>>>(EI, E, N, hist, flags);
    k_scan<<<1, 1024, 0, stream>>>(hist, rowptr, dinv, N);
    k_scatter<<<(E + 255) / 256, 256, 0, stream>>>(EI, E, N, rowptr, cursor, col, flags);

    k_cvtw<<<dim3(16, 4), 256, 0, stream>>>(PREW, GCNW, Pb, Gt, flags);
    k_prepw<<<dim3(64, 3), 256, 0, stream>>>(Pb, Gt, Wt0, Wt1);
    k_prepb<<<2, 256, 0, stream>>>(PREB, Gt, GCNB, cvec, dvec, flags);

    dim3 ggrid((N + 127) / 128, 2);
    k_gemm<<<ggrid, 256, 0, stream>>>(Xb, U, Wt0, cvec, dinv, U, N, 256);
    k_agg<<<(N + 3) / 4, 256, 0, stream>>>(U, rowptr, col, dinv, dvec, Y, N);
    k_gemm<<<ggrid, 256, 0, stream>>>(Xb, Y, Wt1, cvec + 256, dinv, U, N, 512);
    k_agg<<<(N + 3) / 4, 256, 0, stream>>>(U, rowptr, col, dinv, dvec + 256, Y, N);
    k_pool<<<(N + 63) / 64, 256, 0, stream>>>(Y, BATCH, N, psum, pkey, pcnt, flags);
    k_cls<<<64, 64, 0, stream>>>(psum, pkey, pcnt, CLSW, CLSB,
                                 (float*)d_out, (unsigned short*)d_out, flags);
}

// Round 6
// 430.286 us; speedup vs baseline: 1.4250x; 1.2051x over previous
//
#include <hip/hip_runtime.h>

typedef __attribute__((ext_vector_type(8))) short bf16x8;
typedef __attribute__((ext_vector_type(4))) float f32x4;

__device__ inline float bf2f(unsigned short u) {
    union { float f; unsigned int i; } v; v.i = ((unsigned int)u) << 16; return v.f;
}
__device__ inline unsigned short f2bf(float f) {
    union { float f; unsigned int u; } v; v.f = f;
    unsigned int x = v.u;
    unsigned int r = x + 0x7FFFu + ((x >> 16) & 1u);
    return (unsigned short)(r >> 16);
}
// order-preserving float <-> uint for atomicMax
__device__ inline unsigned int fenc(float x) {
    union { float f; unsigned int u; } v; v.f = x;
    return (v.u & 0x80000000u) ? ~v.u : (v.u | 0x80000000u);
}
__device__ inline float fdec(unsigned int k) {
    union { float f; unsigned int u; } v;
    v.u = (k & 0x80000000u) ? (k & 0x7FFFFFFFu) : ~k;
    return v.f;
}
// dual-format loads: f32flag ? float32 buffer : bf16 buffer
__device__ inline float ldf(const void* p, size_t i, int f32) {
    return f32 ? ((const float*)p)[i] : bf2f(((const unsigned short*)p)[i]);
}
// i64flag ? int64 buffer (values < 2^31, take low word) : int32 buffer
__device__ inline int ldi(const int* p, size_t i, int i64) {
    return i64 ? p[2 * i] : p[i];
}

// ---------------- format detection (device-side, deterministic) ----------------
__global__ __launch_bounds__(256)
void k_detect(const unsigned short* __restrict__ xu, int xstride,
              const int* __restrict__ ei, int estride, int* __restrict__ flags) {
    __shared__ int cnt, orv;
    if (threadIdx.x == 0) { cnt = 0; orv = 0; }
    __syncthreads();
    int c = 0, o = 0;
    for (int s = 0; s < 4; ++s) {
        int j = threadIdx.x * 4 + s;               // 0..1023
        size_t k = (size_t)j * xstride;            // < xelems/2
        unsigned short u = xu[2 * k];              // even ushort
        int e = (u >> 7) & 0xFF;
        if (e >= 100 && e <= 140) ++c;             // sane bf16 exponent?
        size_t idx = (size_t)j * estride;          // < E
        o |= ei[2 * idx + 1];                      // odd word
    }
    atomicAdd(&cnt, c); atomicOr(&orv, o);
    __syncthreads();
    if (threadIdx.x == 0) {
        flags[0] = (cnt < 768) ? 1 : 0;   // 1 => floats are f32
        flags[1] = (orv == 0) ? 1 : 0;    // 1 => ints are int64
    }
}

// ---------------- zero scratch ----------------
__global__ void k_zero(int* __restrict__ hist, int* __restrict__ cursor,
                       float* __restrict__ psum, unsigned int* __restrict__ pkey,
                       int* __restrict__ pcnt, int N) {
    int t = blockIdx.x * 256 + threadIdx.x;
    if (t < N) hist[t] = 0;
    else if (t < 2 * N) cursor[t - N] = 0;
    else if (t < 2 * N + 16384) psum[t - 2 * N] = 0.f;
    else if (t < 2 * N + 32768) pkey[t - 2 * N - 16384] = 0u;
    else if (t < 2 * N + 32768 + 64) pcnt[t - 2 * N - 32768] = 0;
}

// ---------------- X -> bf16 conversion (or copy if already bf16) ----------------
__global__ __launch_bounds__(256)
void k_cvt(const void* __restrict__ X, unsigned short* __restrict__ Xb,
           size_t nelem, const int* __restrict__ flags) {
    int f = flags[0];
    size_t i = ((size_t)blockIdx.x * 256 + threadIdx.x) * 8;
    if (i >= nelem) return;
    if (f) {
        const float* s = (const float*)X + i;
        float4 f0 = *(const float4*)s;
        float4 f1 = *(const float4*)(s + 4);
        int4 o;
        o.x = (int)f2bf(f0.x) | ((int)f2bf(f0.y) << 16);
        o.y = (int)f2bf(f0.z) | ((int)f2bf(f0.w) << 16);
        o.z = (int)f2bf(f1.x) | ((int)f2bf(f1.y) << 16);
        o.w = (int)f2bf(f1.z) | ((int)f2bf(f1.w) << 16);
        *(int4*)(Xb + i) = o;
    } else {
        *(int4*)(Xb + i) = *(const int4*)((const unsigned short*)X + i);
    }
}

// ---------------- weight convert + transpose ----------------
// Pb[i][k][m] = bf16(pre_w[i][k][m])      (straight convert)
// Gt[i][n][m] = bf16(gcn_w[i][m][n])      (transpose via padded LDS tile)
// grid (16, 4): 4 products x 16 64x64 tiles, 256 thr.
__global__ __launch_bounds__(256)
void k_cvtw(const void* __restrict__ pre_w, const void* __restrict__ gcn_w,
            unsigned short* __restrict__ Pb, unsigned short* __restrict__ Gt,
            const int* __restrict__ flags) {
    __shared__ float tile[64][65];
    const int i = blockIdx.y;
    const int m0 = (blockIdx.x & 3) * 64;
    const int n0 = (blockIdx.x >> 2) * 64;
    const int f = flags[0];
    const size_t base = (size_t)i * 65536;
#pragma unroll
    for (int q = 0; q < 16; ++q) {
        int idx = q * 256 + threadIdx.x;
        int r = idx >> 6, c = idx & 63;
        size_t src = base + (size_t)(m0 + r) * 256 + n0 + c;
        Pb[src] = f2bf(ldf(pre_w, src, f));
        tile[r][c] = ldf(gcn_w, src, f);
    }
    __syncthreads();
#pragma unroll
    for (int q = 0; q < 16; ++q) {
        int idx = q * 256 + threadIdx.x;
        int r = idx >> 6, c = idx & 63;
        Gt[base + (size_t)(n0 + r) * 256 + m0 + c] = f2bf(tile[c][r]);
    }
}

// ---------------- weight folding via MFMA ----------------
// Q^T[n][k] = sum_m Gt[n][m] * P[k][m]   (A = Gt rows, B = P rows, both contiguous)
// which=0: Wt0[n*256+k]     = 2*Q0^T + Q1^T
// which=1: Wt1[n*512+k]     = 2*Q2^T
// which=2: Wt1[n*512+256+k] =   Q3^T
// grid (64, 3), 256 thr = 4 waves; each wave one 16(n) x 16(k) tile, K=256.
__global__ __launch_bounds__(256)
void k_prepw(const unsigned short* __restrict__ Pb, const unsigned short* __restrict__ Gt,
             unsigned short* __restrict__ Wt0, unsigned short* __restrict__ Wt1) {
    const int which = blockIdx.y;
    const int wid = threadIdx.x >> 6, lane = threadIdx.x & 63;
    const int tile = blockIdx.x * 4 + wid;       // 0..255
    const int n0 = (tile >> 4) * 16, k0 = (tile & 15) * 16;
    const int l15 = lane & 15, hi = lane >> 4;
    size_t base0, base1 = 0;
    if (which == 0)      { base0 = 0; base1 = 65536; }
    else if (which == 1) { base0 = 2 * 65536; }
    else                 { base0 = 3 * 65536; }
    f32x4 acc0 = {}, acc1 = {};
    const unsigned short* ga = Gt + base0 + (size_t)(n0 + l15) * 256 + hi * 8;
    const unsigned short* pa = Pb + base0 + (size_t)(k0 + l15) * 256 + hi * 8;
    const unsigned short* gb = Gt + base1 + (size_t)(n0 + l15) * 256 + hi * 8;
    const unsigned short* pb = Pb + base1 + (size_t)(k0 + l15) * 256 + hi * 8;
#pragma unroll
    for (int kt = 0; kt < 8; ++kt) {
        bf16x8 a0 = *(const bf16x8*)(ga + kt * 32);
        bf16x8 b0 = *(const bf16x8*)(pa + kt * 32);
        acc0 = __builtin_amdgcn_mfma_f32_16x16x32_bf16(a0, b0, acc0, 0, 0, 0);
        if (which == 0) {
            bf16x8 a1 = *(const bf16x8*)(gb + kt * 32);
            bf16x8 b1 = *(const bf16x8*)(pb + kt * 32);
            acc1 = __builtin_amdgcn_mfma_f32_16x16x32_bf16(a1, b1, acc1, 0, 0, 0);
        }
    }
#pragma unroll
    for (int j = 0; j < 4; ++j) {
        int n = n0 + hi * 4 + j;
        int k = k0 + l15;
        if (which == 0)      Wt0[(size_t)n * 256 + k]       = f2bf(2.f * acc0[j] + acc1[j]);
        else if (which == 1) Wt1[(size_t)n * 512 + k]       = f2bf(2.f * acc0[j]);
        else                 Wt1[(size_t)n * 512 + 256 + k] = f2bf(acc0[j]);
    }
}

// ---------------- bias folding (uses Gt: contiguous bf16 rows) ----------------
__global__ __launch_bounds__(256)
void k_prepb(const void* __restrict__ pre_b, const unsigned short* __restrict__ Gt,
             const void* __restrict__ gcn_b,
             float* __restrict__ cvec, float* __restrict__ dvec,
             const int* __restrict__ flags) {
    __shared__ float pb[2][256];
    const int l = blockIdx.x, n = threadIdx.x;
    const int f = flags[0];
    pb[0][n] = ldf(pre_b, (size_t)(l * 2 + 0) * 256 + n, f);
    pb[1][n] = ldf(pre_b, (size_t)(l * 2 + 1) * 256 + n, f);
    __syncthreads();
    const unsigned short* g0 = Gt + (size_t)(l * 2 + 0) * 65536 + (size_t)n * 256;
    const unsigned short* g1 = Gt + (size_t)(l * 2 + 1) * 65536 + (size_t)n * 256;
    float a = 0.f, b = 0.f;
#pragma unroll 4
    for (int mc = 0; mc < 32; ++mc) {
        bf16x8 v0 = *(const bf16x8*)(g0 + mc * 8);
        bf16x8 v1 = *(const bf16x8*)(g1 + mc * 8);
#pragma unroll
        for (int u = 0; u < 8; ++u) {
            a += pb[0][mc * 8 + u] * bf2f((unsigned short)v0[u]);
            b += pb[1][mc * 8 + u] * bf2f((unsigned short)v1[u]);
        }
    }
    cvec[l * 256 + n] = 2.f * a + b;
    dvec[l * 256 + n] = 2.f * ldf(gcn_b, (size_t)(l * 2 + 0) * 256 + n, f)
                            + ldf(gcn_b, (size_t)(l * 2 + 1) * 256 + n, f);
}

// ---------------- CSR build ----------------
__global__ void k_hist(const int* __restrict__ ei, int E, int N,
                       int* __restrict__ hist, const int* __restrict__ flags) {
    int e = blockIdx.x * 256 + threadIdx.x;
    if (e >= E) return;
    int i64 = flags[1];
    int d = ldi(ei, (size_t)E + e, i64); d = d < 0 ? 0 : (d >= N ? N - 1 : d);
    atomicAdd(&hist[d], 1);
}

// hierarchical coalesced scan: pass 1 = per-block exclusive prefix + block sum
__global__ __launch_bounds__(256)
void k_scan1(const int* __restrict__ hist, int* __restrict__ pre,
             int* __restrict__ bsum, int N) {
    __shared__ int s[256];
    int i = blockIdx.x * 256 + threadIdx.x;
    int v = (i < N) ? hist[i] : 0;
    s[threadIdx.x] = v;
    __syncthreads();
    for (int off = 1; off < 256; off <<= 1) {
        int t = (threadIdx.x >= off) ? s[threadIdx.x - off] : 0;
        __syncthreads();
        s[threadIdx.x] += t;
        __syncthreads();
    }
    if (i < N) pre[i] = s[threadIdx.x] - v;          // exclusive within block
    if (threadIdx.x == 255) bsum[blockIdx.x] = s[255];
}

// pass 2: scan block sums (nb <= 256) into boff; write rowptr[N] = total
__global__ __launch_bounds__(256)
void k_scan2(const int* __restrict__ bsum, int* __restrict__ boff,
             int* __restrict__ rowptr, int nb, int N) {
    __shared__ int s[256];
    int t = threadIdx.x;
    int v = (t < nb) ? bsum[t] : 0;
    s[t] = v;
    __syncthreads();
    for (int off = 1; off < 256; off <<= 1) {
        int x = (t >= off) ? s[t - off] : 0;
        __syncthreads();
        s[t] += x;
        __syncthreads();
    }
    if (t < nb) boff[t] = s[t] - v;                  // exclusive block offset
    if (t == nb - 1) rowptr[N] = s[t];               // grand total
}

// pass 3: final rowptr + dinv (all coalesced)
__global__ __launch_bounds__(256)
void k_scan3(const int* __restrict__ hist, const int* __restrict__ pre,
             const int* __restrict__ boff, int* __restrict__ rowptr,
             float* __restrict__ dinv, int N) {
    int i = blockIdx.x * 256 + threadIdx.x;
    if (i < N) {
        rowptr[i] = pre[i] + boff[blockIdx.x];
        dinv[i] = rsqrtf((float)(hist[i] + 1));
    }
}

__global__ void k_scatter(const int* __restrict__ ei, int E, int N,
                          const int* __restrict__ rowptr, int* __restrict__ cursor,
                          int* __restrict__ col, const int* __restrict__ flags) {
    int e = blockIdx.x * 256 + threadIdx.x;
    if (e >= E) return;
    int i64 = flags[1];
    int s = ldi(ei, (size_t)e, i64);     s = s < 0 ? 0 : (s >= N ? N - 1 : s);
    int d = ldi(ei, (size_t)E + e, i64); d = d < 0 ? 0 : (d >= N ? N - 1 : d);
    int pos = rowptr[d] + atomicAdd(&cursor[d], 1);
    col[pos] = s;
}

// ---------------- main GEMM: out[i,:] = dinv[i] * (A[i,:] @ W + c) ----------------
// A row: k<256 from Xb (bf16), k>=256 from Yb (bf16). Wt is [256 x K] bf16 (W^T).
// 128x128 tile, BK=64, 4 waves (2x2), XOR-swizzled LDS.
__global__ __launch_bounds__(256)
void k_gemm(const unsigned short* __restrict__ Xb, const unsigned short* __restrict__ Yb,
            const unsigned short* __restrict__ Wt, const float* __restrict__ cvec,
            const float* __restrict__ dinv, unsigned short* __restrict__ out,
            int M, int K) {
    __shared__ unsigned short lds[2 * 128 * 64];  // A tile + W tile, 16KB each
    char* ldsb = (char*)lds;
    const int tid = threadIdx.x;
    const int lane = tid & 63;
    const int wid = tid >> 6;
    const int wm = wid >> 1, wn = wid & 1;
    const int row0 = blockIdx.x * 128;
    const int bn = blockIdx.y;

    f32x4 acc[4][4] = {};
    const int KT = K / 64;
    for (int kt = 0; kt < KT; ++kt) {
        const int k0 = kt * 64;
        const unsigned short* Asrc = (k0 < 256) ? Xb : Yb;
        const int ak0 = (k0 < 256) ? k0 : k0 - 256;
        int4 ra[4], rw[4];
#pragma unroll
        for (int q = 0; q < 4; ++q) {
            int id = q * 256 + tid;        // 0..1023 chunks of 16B (8 bf16)
            int r = id >> 3;               // tile row 0..127
            int cb = id & 7;               // chunk in row
            int grow = row0 + r; if (grow > M - 1) grow = M - 1;
            ra[q] = *(const int4*)(Asrc + (size_t)grow * 256 + ak0 + cb * 8);
            rw[q] = *(const int4*)(Wt + (size_t)(bn * 128 + r) * K + k0 + cb * 8);
        }
        __syncthreads();   // prior LDS reads done
#pragma unroll
        for (int q = 0; q < 4; ++q) {
            int id = q * 256 + tid;
            int r = id >> 3, cb = id & 7;
            int sw = (cb * 16) ^ ((r & 7) << 4);
            *(int4*)(ldsb + r * 128 + sw) = ra[q];
            *(int4*)(ldsb + 16384 + r * 128 + sw) = rw[q];
        }
        __syncthreads();
#pragma unroll
        for (int kk = 0; kk < 2; ++kk) {
            bf16x8 af[4], bfr[4];
            int byte = kk * 64 + ((lane >> 4) << 4);
#pragma unroll
            for (int m = 0; m < 4; ++m) {
                int r = wm * 64 + m * 16 + (lane & 15);
                af[m] = *(const bf16x8*)(ldsb + r * 128 + (byte ^ ((r & 7) << 4)));
            }
#pragma unroll
            for (int n = 0; n < 4; ++n) {
                int r = wn * 64 + n * 16 + (lane & 15);
                bfr[n] = *(const bf16x8*)(ldsb + 16384 + r * 128 + (byte ^ ((r & 7) << 4)));
            }
#pragma unroll
            for (int m = 0; m < 4; ++m)
#pragma unroll
                for (int n = 0; n < 4; ++n)
                    acc[m][n] = __builtin_amdgcn_mfma_f32_16x16x32_bf16(af[m], bfr[n], acc[m][n], 0, 0, 0);
        }
    }
    // epilogue: val = (acc + c[col]) * dinv[row], bf16 store
#pragma unroll
    for (int m = 0; m < 4; ++m) {
#pragma unroll
        for (int j = 0; j < 4; ++j) {
            int rt = wm * 64 + m * 16 + ((lane >> 4) << 2) + j;
            int grow = row0 + rt;
            if (grow < M) {
                float di = dinv[grow];
#pragma unroll
                for (int n = 0; n < 4; ++n) {
                    int colc = bn * 128 + wn * 64 + n * 16 + (lane & 15);
                    float v = (acc[m][n][j] + cvec[colc]) * di;
                    out[(size_t)grow * 256 + colc] = f2bf(v);
                }
            }
        }
    }
}

// ---------------- aggregation: Y[i] = dinv[i]*(U[i] + sum_{j in in(i)} U[j]) + d ----------------
// wave = one node; 16-deep gather MLP, then 4-deep, then scalar tail.
__global__ __launch_bounds__(256)
void k_agg(const unsigned short* __restrict__ U, const int* __restrict__ rowptr,
           const int* __restrict__ col, const float* __restrict__ dinv,
           const float* __restrict__ dvec, unsigned short* __restrict__ Y, int N) {
    int w = (blockIdx.x * 256 + threadIdx.x) >> 6;   // node per wave
    int lane = threadIdx.x & 63;
    if (w >= N) return;
    const size_t loff = (size_t)lane * 4;
    ushort4 sv = *(const ushort4*)(U + (size_t)w * 256 + loff);
    float a0 = bf2f(sv.x), a1 = bf2f(sv.y), a2 = bf2f(sv.z), a3 = bf2f(sv.w);
    int beg = rowptr[w], end = rowptr[w + 1];
    int e = beg;
    for (; e + 16 <= end; e += 16) {
        int s[16];
        ushort4 v[16];
#pragma unroll
        for (int u = 0; u < 16; ++u) s[u] = __builtin_amdgcn_readfirstlane(col[e + u]);
#pragma unroll
        for (int u = 0; u < 16; ++u) v[u] = *(const ushort4*)(U + (size_t)s[u] * 256 + loff);
#pragma unroll
        for (int u = 0; u < 16; ++u) {
            a0 += bf2f(v[u].x); a1 += bf2f(v[u].y);
            a2 += bf2f(v[u].z); a3 += bf2f(v[u].w);
        }
    }
    for (; e + 4 <= end; e += 4) {
        int s[4];
        ushort4 v[4];
#pragma unroll
        for (int u = 0; u < 4; ++u) s[u] = __builtin_amdgcn_readfirstlane(col[e + u]);
#pragma unroll
        for (int u = 0; u < 4; ++u) v[u] = *(const ushort4*)(U + (size_t)s[u] * 256 + loff);
#pragma unroll
        for (int u = 0; u < 4; ++u) {
            a0 += bf2f(v[u].x); a1 += bf2f(v[u].y);
            a2 += bf2f(v[u].z); a3 += bf2f(v[u].w);
        }
    }
    for (; e < end; ++e) {
        int s = __builtin_amdgcn_readfirstlane(col[e]);
        ushort4 v = *(const ushort4*)(U + (size_t)s * 256 + loff);
        a0 += bf2f(v.x); a1 += bf2f(v.y); a2 += bf2f(v.z); a3 += bf2f(v.w);
    }
    float di = dinv[w];
    int f = lane * 4;
    a0 = a0 * di + dvec[f + 0];
    a1 = a1 * di + dvec[f + 1];
    a2 = a2 * di + dvec[f + 2];
    a3 = a3 * di + dvec[f + 3];
    ushort4 o; o.x = f2bf(a0); o.y = f2bf(a1); o.z = f2bf(a2); o.w = f2bf(a3);
    *(ushort4*)(Y + (size_t)w * 256 + loff) = o;
}

// ---------------- pooling (batch is sorted) ----------------
__global__ __launch_bounds__(256)
void k_pool(const unsigned short* __restrict__ Y, const int* __restrict__ batch, int N,
            float* __restrict__ psum, unsigned int* __restrict__ pkey, int* __restrict__ pcnt,
            const int* __restrict__ flags) {
    int f = threadIdx.x;
    int base = blockIdx.x * 64;
    if (base >= N) return;
    int i64 = flags[1];
    int g0 = ldi(batch, base, i64); int curg = g0 < 0 ? 0 : (g0 > 63 ? 63 : g0);
    float s = 0.f, mx = -__builtin_inff(); int cnt = 0;
#pragma unroll 4
    for (int r = 0; r < 64; ++r) {
        int node = base + r;
        if (node >= N) break;
        int g = ldi(batch, node, i64); g = g < 0 ? 0 : (g > 63 ? 63 : g);
        if (g != curg) {
            atomicAdd(&psum[curg * 256 + f], s);
            atomicMax(&pkey[curg * 256 + f], fenc(mx));
            if (f == 0) atomicAdd(&pcnt[curg], cnt);
            curg = g; s = 0.f; mx = -__builtin_inff(); cnt = 0;
        }
        float v = bf2f(Y[(size_t)node * 256 + f]);
        s += v; mx = fmaxf(mx, v); ++cnt;
    }
    atomicAdd(&psum[curg * 256 + f], s);
    atomicMax(&pkey[curg * 256 + f], fenc(mx));
    if (f == 0) atomicAdd(&pcnt[curg], cnt);
}

// ---------------- classifier ----------------
__global__ __launch_bounds__(64)
void k_cls(const float* __restrict__ psum, const unsigned int* __restrict__ pkey,
           const int* __restrict__ pcnt, const void* __restrict__ clsw,
           const void* __restrict__ clsb, float* __restrict__ outf,
           unsigned short* __restrict__ outu, const int* __restrict__ flags) {
    __shared__ float pooled[256];
    int g = blockIdx.x, c = threadIdx.x;
    int f = flags[0];
    int cnt = pcnt[g];
    for (int m = c; m < 256; m += 64) {
        float mean = psum[g * 256 + m] / (float)(cnt > 0 ? cnt : 1);
        float mx = (cnt > 0) ? fdec(pkey[g * 256 + m]) : 0.f;
        pooled[m] = mean + mx;
    }
    __syncthreads();
    float a = ldf(clsb, c, f);
#pragma unroll 8
    for (int m = 0; m < 256; ++m) a += pooled[m] * ldf(clsw, (size_t)m * 64 + c, f);
    if (f) outf[g * 64 + c] = a;
    else   outu[g * 64 + c] = f2bf(a);
}

extern "C" void kernel_launch(void* const* d_in, const int* in_sizes, int n_in,
                              void* d_out, int out_size, void* d_ws, size_t ws_size,
                              hipStream_t stream) {
    const void*           X     = d_in[0];
    const int*            EI    = (const int*)d_in[1];
    const int*            BATCH = (const int*)d_in[3];
    const void*           PREW  = d_in[4];
    const void*           PREB  = d_in[5];
    const void*           GCNW  = d_in[6];
    const void*           GCNB  = d_in[7];
    const void*           CLSW  = d_in[8];
    const void*           CLSB  = d_in[9];

    const int N = in_sizes[3];
    const int E = in_sizes[1] / 2;
    const int NB = (N + 255) / 256;

    char* ws = (char*)d_ws;
    size_t off = 0;
    auto alloc = [&](size_t b) { size_t o = off; off += (b + 255) & ~(size_t)255; return o; };
    int*            flags  = (int*)(ws + alloc(256));
    float*          dinv   = (float*)(ws + alloc((size_t)N * 4));
    int*            hist   = (int*)(ws + alloc((size_t)N * 4));
    int*            cursor = (int*)(ws + alloc((size_t)N * 4));
    int*            rowptr = (int*)(ws + alloc((size_t)(N + 1) * 4));
    int*            pre    = (int*)(ws + alloc((size_t)N * 4));
    int*            bsum   = (int*)(ws + alloc((size_t)NB * 4));
    int*            boff   = (int*)(ws + alloc((size_t)NB * 4));
    int*            col    = (int*)(ws + alloc((size_t)E * 4));
    unsigned short* Pb     = (unsigned short*)(ws + alloc(4 * 65536 * 2));
    unsigned short* Gt     = (unsigned short*)(ws + alloc(4 * 65536 * 2));
    unsigned short* Wt0    = (unsigned short*)(ws + alloc(256 * 256 * 2));
    unsigned short* Wt1    = (unsigned short*)(ws + alloc(256 * 512 * 2));
    float*          cvec   = (float*)(ws + alloc(512 * 4));
    float*          dvec   = (float*)(ws + alloc(512 * 4));
    float*          psum   = (float*)(ws + alloc(64 * 256 * 4));
    unsigned int*   pkey   = (unsigned int*)(ws + alloc(64 * 256 * 4));
    int*            pcnt   = (int*)(ws + alloc(64 * 4));
    unsigned short* Xb     = (unsigned short*)(ws + alloc((size_t)N * 256 * 2));
    unsigned short* U      = (unsigned short*)(ws + alloc((size_t)N * 256 * 2));
    unsigned short* Y      = (unsigned short*)(ws + alloc((size_t)N * 256 * 2));

    int zt = 2 * N + 32768 + 64;
    k_zero<<<(zt + 255) / 256, 256, 0, stream>>>(hist, cursor, psum, pkey, pcnt, N);

    int xstride = (in_sizes[0] / 2) / 1024; if (xstride < 1) xstride = 1;
    int estride = E / 1024;                 if (estride < 1) estride = 1;
    k_detect<<<1, 256, 0, stream>>>((const unsigned short*)X, xstride, EI, estride, flags);

    size_t xelem = (size_t)N * 256;
    k_cvt<<<(int)((xelem / 8 + 255) / 256), 256, 0, stream>>>(X, Xb, xelem, flags);

    k_hist<<<(E + 255) / 256, 256, 0, stream>>>(EI, E, N, hist, flags);
    k_scan1<<<NB, 256, 0, stream>>>(hist, pre, bsum, N);
    k_scan2<<<1, 256, 0, stream>>>(bsum, boff, rowptr, NB, N);
    k_scan3<<<NB, 256, 0, stream>>>(hist, pre, boff, rowptr, dinv, N);
    k_scatter<<<(E + 255) / 256, 256, 0, stream>>>(EI, E, N, rowptr, cursor, col, flags);

    k_cvtw<<<dim3(16, 4), 256, 0, stream>>>(PREW, GCNW, Pb, Gt, flags);
    k_prepw<<<dim3(64, 3), 256, 0, stream>>>(Pb, Gt, Wt0, Wt1);
    k_prepb<<<2, 256, 0, stream>>>(PREB, Gt, GCNB, cvec, dvec, flags);

    dim3 ggrid((N + 127) / 128, 2);
    k_gemm<<<ggrid, 256, 0, stream>>>(Xb, U, Wt0, cvec, dinv, U, N, 256);
    k_agg<<<(N + 3) / 4, 256, 0, stream>>>(U, rowptr, col, dinv, dvec, Y, N);
    k_gemm<<<ggrid, 256, 0, stream>>>(Xb, Y, Wt1, cvec + 256, dinv, U, N, 512);
    k_agg<<<(N + 3) / 4, 256, 0, stream>>>(U, rowptr, col, dinv, dvec + 256, Y, N);
    k_pool<<<(N + 63) / 64, 256, 0, stream>>>(Y, BATCH, N, psum, pkey, pcnt, flags);
    k_cls<<<64, 64, 0, stream>>>(psum, pkey, pcnt, CLSW, CLSB,
                                 (float*)d_out, (unsigned short*)d_out, flags);
}

// Round 7
// 403.522 us; speedup vs baseline: 1.5195x; 1.0663x over previous
//
#include <hip/hip_runtime.h>

typedef __attribute__((ext_vector_type(8))) short bf16x8;
typedef __attribute__((ext_vector_type(4))) float f32x4;

__device__ inline float bf2f(unsigned short u) {
    union { float f; unsigned int i; } v; v.i = ((unsigned int)u) << 16; return v.f;
}
__device__ inline unsigned short f2bf(float f) {
    union { float f; unsigned int u; } v; v.f = f;
    unsigned int x = v.u;
    unsigned int r = x + 0x7FFFu + ((x >> 16) & 1u);
    return (unsigned short)(r >> 16);
}
// order-preserving float <-> uint for atomicMax
__device__ inline unsigned int fenc(float x) {
    union { float f; unsigned int u; } v; v.f = x;
    return (v.u & 0x80000000u) ? ~v.u : (v.u | 0x80000000u);
}
__device__ inline float fdec(unsigned int k) {
    union { float f; unsigned int u; } v;
    v.u = (k & 0x80000000u) ? (k & 0x7FFFFFFFu) : ~k;
    return v.f;
}
// dual-format loads: f32flag ? float32 buffer : bf16 buffer
__device__ inline float ldf(const void* p, size_t i, int f32) {
    return f32 ? ((const float*)p)[i] : bf2f(((const unsigned short*)p)[i]);
}
// i64flag ? int64 buffer (values < 2^31, take low word) : int32 buffer
__device__ inline int ldi(const int* p, size_t i, int i64) {
    return i64 ? p[2 * i] : p[i];
}

// ---------------- format detection (device-side, deterministic) ----------------
__global__ __launch_bounds__(256)
void k_detect(const unsigned short* __restrict__ xu, int xstride,
              const int* __restrict__ ei, int estride, int* __restrict__ flags) {
    __shared__ int cnt, orv;
    if (threadIdx.x == 0) { cnt = 0; orv = 0; }
    __syncthreads();
    int c = 0, o = 0;
    for (int s = 0; s < 4; ++s) {
        int j = threadIdx.x * 4 + s;               // 0..1023
        size_t k = (size_t)j * xstride;            // < xelems/2
        unsigned short u = xu[2 * k];              // even ushort
        int e = (u >> 7) & 0xFF;
        if (e >= 100 && e <= 140) ++c;             // sane bf16 exponent?
        size_t idx = (size_t)j * estride;          // < E
        o |= ei[2 * idx + 1];                      // odd word
    }
    atomicAdd(&cnt, c); atomicOr(&orv, o);
    __syncthreads();
    if (threadIdx.x == 0) {
        flags[0] = (cnt < 768) ? 1 : 0;   // 1 => floats are f32
        flags[1] = (orv == 0) ? 1 : 0;    // 1 => ints are int64
    }
}

// ---------------- zero scratch ----------------
__global__ void k_zero(int* __restrict__ hist, int* __restrict__ cursor,
                       float* __restrict__ psum, unsigned int* __restrict__ pkey,
                       int* __restrict__ pcnt, int N) {
    int t = blockIdx.x * 256 + threadIdx.x;
    if (t < N) hist[t] = 0;
    else if (t < 2 * N) cursor[t - N] = 0;
    else if (t < 2 * N + 16384) psum[t - 2 * N] = 0.f;
    else if (t < 2 * N + 32768) pkey[t - 2 * N - 16384] = 0u;
    else if (t < 2 * N + 32768 + 64) pcnt[t - 2 * N - 32768] = 0;
}

// ---------------- X -> bf16 conversion (or copy if already bf16) ----------------
__global__ __launch_bounds__(256)
void k_cvt(const void* __restrict__ X, unsigned short* __restrict__ Xb,
           size_t nelem, const int* __restrict__ flags) {
    int f = flags[0];
    size_t i = ((size_t)blockIdx.x * 256 + threadIdx.x) * 8;
    if (i >= nelem) return;
    if (f) {
        const float* s = (const float*)X + i;
        float4 f0 = *(const float4*)s;
        float4 f1 = *(const float4*)(s + 4);
        int4 o;
        o.x = (int)f2bf(f0.x) | ((int)f2bf(f0.y) << 16);
        o.y = (int)f2bf(f0.z) | ((int)f2bf(f0.w) << 16);
        o.z = (int)f2bf(f1.x) | ((int)f2bf(f1.y) << 16);
        o.w = (int)f2bf(f1.z) | ((int)f2bf(f1.w) << 16);
        *(int4*)(Xb + i) = o;
    } else {
        *(int4*)(Xb + i) = *(const int4*)((const unsigned short*)X + i);
    }
}

// ---------------- weight convert + transpose ----------------
__global__ __launch_bounds__(256)
void k_cvtw(const void* __restrict__ pre_w, const void* __restrict__ gcn_w,
            unsigned short* __restrict__ Pb, unsigned short* __restrict__ Gt,
            const int* __restrict__ flags) {
    __shared__ float tile[64][65];
    const int i = blockIdx.y;
    const int m0 = (blockIdx.x & 3) * 64;
    const int n0 = (blockIdx.x >> 2) * 64;
    const int f = flags[0];
    const size_t base = (size_t)i * 65536;
#pragma unroll
    for (int q = 0; q < 16; ++q) {
        int idx = q * 256 + threadIdx.x;
        int r = idx >> 6, c = idx & 63;
        size_t src = base + (size_t)(m0 + r) * 256 + n0 + c;
        Pb[src] = f2bf(ldf(pre_w, src, f));
        tile[r][c] = ldf(gcn_w, src, f);
    }
    __syncthreads();
#pragma unroll
    for (int q = 0; q < 16; ++q) {
        int idx = q * 256 + threadIdx.x;
        int r = idx >> 6, c = idx & 63;
        Gt[base + (size_t)(n0 + r) * 256 + m0 + c] = f2bf(tile[c][r]);
    }
}

// ---------------- weight folding via MFMA ----------------
__global__ __launch_bounds__(256)
void k_prepw(const unsigned short* __restrict__ Pb, const unsigned short* __restrict__ Gt,
             unsigned short* __restrict__ Wt0, unsigned short* __restrict__ Wt1) {
    const int which = blockIdx.y;
    const int wid = threadIdx.x >> 6, lane = threadIdx.x & 63;
    const int tile = blockIdx.x * 4 + wid;       // 0..255
    const int n0 = (tile >> 4) * 16, k0 = (tile & 15) * 16;
    const int l15 = lane & 15, hi = lane >> 4;
    size_t base0, base1 = 0;
    if (which == 0)      { base0 = 0; base1 = 65536; }
    else if (which == 1) { base0 = 2 * 65536; }
    else                 { base0 = 3 * 65536; }
    f32x4 acc0 = {}, acc1 = {};
    const unsigned short* ga = Gt + base0 + (size_t)(n0 + l15) * 256 + hi * 8;
    const unsigned short* pa = Pb + base0 + (size_t)(k0 + l15) * 256 + hi * 8;
    const unsigned short* gb = Gt + base1 + (size_t)(n0 + l15) * 256 + hi * 8;
    const unsigned short* pb = Pb + base1 + (size_t)(k0 + l15) * 256 + hi * 8;
#pragma unroll
    for (int kt = 0; kt < 8; ++kt) {
        bf16x8 a0 = *(const bf16x8*)(ga + kt * 32);
        bf16x8 b0 = *(const bf16x8*)(pa + kt * 32);
        acc0 = __builtin_amdgcn_mfma_f32_16x16x32_bf16(a0, b0, acc0, 0, 0, 0);
        if (which == 0) {
            bf16x8 a1 = *(const bf16x8*)(gb + kt * 32);
            bf16x8 b1 = *(const bf16x8*)(pb + kt * 32);
            acc1 = __builtin_amdgcn_mfma_f32_16x16x32_bf16(a1, b1, acc1, 0, 0, 0);
        }
    }
#pragma unroll
    for (int j = 0; j < 4; ++j) {
        int n = n0 + hi * 4 + j;
        int k = k0 + l15;
        if (which == 0)      Wt0[(size_t)n * 256 + k]       = f2bf(2.f * acc0[j] + acc1[j]);
        else if (which == 1) Wt1[(size_t)n * 512 + k]       = f2bf(2.f * acc0[j]);
        else                 Wt1[(size_t)n * 512 + 256 + k] = f2bf(acc0[j]);
    }
}

// ---------------- bias folding (uses Gt: contiguous bf16 rows) ----------------
__global__ __launch_bounds__(256)
void k_prepb(const void* __restrict__ pre_b, const unsigned short* __restrict__ Gt,
             const void* __restrict__ gcn_b,
             float* __restrict__ cvec, float* __restrict__ dvec,
             const int* __restrict__ flags) {
    __shared__ float pb[2][256];
    const int l = blockIdx.x, n = threadIdx.x;
    const int f = flags[0];
    pb[0][n] = ldf(pre_b, (size_t)(l * 2 + 0) * 256 + n, f);
    pb[1][n] = ldf(pre_b, (size_t)(l * 2 + 1) * 256 + n, f);
    __syncthreads();
    const unsigned short* g0 = Gt + (size_t)(l * 2 + 0) * 65536 + (size_t)n * 256;
    const unsigned short* g1 = Gt + (size_t)(l * 2 + 1) * 65536 + (size_t)n * 256;
    float a = 0.f, b = 0.f;
#pragma unroll 4
    for (int mc = 0; mc < 32; ++mc) {
        bf16x8 v0 = *(const bf16x8*)(g0 + mc * 8);
        bf16x8 v1 = *(const bf16x8*)(g1 + mc * 8);
#pragma unroll
        for (int u = 0; u < 8; ++u) {
            a += pb[0][mc * 8 + u] * bf2f((unsigned short)v0[u]);
            b += pb[1][mc * 8 + u] * bf2f((unsigned short)v1[u]);
        }
    }
    cvec[l * 256 + n] = 2.f * a + b;
    dvec[l * 256 + n] = 2.f * ldf(gcn_b, (size_t)(l * 2 + 0) * 256 + n, f)
                            + ldf(gcn_b, (size_t)(l * 2 + 1) * 256 + n, f);
}

// ---------------- CSR build ----------------
__global__ void k_hist(const int* __restrict__ ei, int E, int N,
                       int* __restrict__ hist, const int* __restrict__ flags) {
    int e = blockIdx.x * 256 + threadIdx.x;
    if (e >= E) return;
    int i64 = flags[1];
    int d = ldi(ei, (size_t)E + e, i64); d = d < 0 ? 0 : (d >= N ? N - 1 : d);
    atomicAdd(&hist[d], 1);
}

__global__ __launch_bounds__(256)
void k_scan1(const int* __restrict__ hist, int* __restrict__ pre,
             int* __restrict__ bsum, int N) {
    __shared__ int s[256];
    int i = blockIdx.x * 256 + threadIdx.x;
    int v = (i < N) ? hist[i] : 0;
    s[threadIdx.x] = v;
    __syncthreads();
    for (int off = 1; off < 256; off <<= 1) {
        int t = (threadIdx.x >= off) ? s[threadIdx.x - off] : 0;
        __syncthreads();
        s[threadIdx.x] += t;
        __syncthreads();
    }
    if (i < N) pre[i] = s[threadIdx.x] - v;          // exclusive within block
    if (threadIdx.x == 255) bsum[blockIdx.x] = s[255];
}

__global__ __launch_bounds__(256)
void k_scan2(const int* __restrict__ bsum, int* __restrict__ boff,
             int* __restrict__ rowptr, int nb, int N) {
    __shared__ int s[256];
    int t = threadIdx.x;
    int v = (t < nb) ? bsum[t] : 0;
    s[t] = v;
    __syncthreads();
    for (int off = 1; off < 256; off <<= 1) {
        int x = (t >= off) ? s[t - off] : 0;
        __syncthreads();
        s[t] += x;
        __syncthreads();
    }
    if (t < nb) boff[t] = s[t] - v;                  // exclusive block offset
    if (t == nb - 1) rowptr[N] = s[t];               // grand total
}

__global__ __launch_bounds__(256)
void k_scan3(const int* __restrict__ hist, const int* __restrict__ pre,
             const int* __restrict__ boff, int* __restrict__ rowptr,
             float* __restrict__ dinv, int N) {
    int i = blockIdx.x * 256 + threadIdx.x;
    if (i < N) {
        rowptr[i] = pre[i] + boff[blockIdx.x];
        dinv[i] = rsqrtf((float)(hist[i] + 1));
    }
}

__global__ void k_scatter(const int* __restrict__ ei, int E, int N,
                          const int* __restrict__ rowptr, int* __restrict__ cursor,
                          int* __restrict__ col, const int* __restrict__ flags) {
    int e = blockIdx.x * 256 + threadIdx.x;
    if (e >= E) return;
    int i64 = flags[1];
    int s = ldi(ei, (size_t)e, i64);     s = s < 0 ? 0 : (s >= N ? N - 1 : s);
    int d = ldi(ei, (size_t)E + e, i64); d = d < 0 ? 0 : (d >= N ? N - 1 : d);
    int pos = rowptr[d] + atomicAdd(&cursor[d], 1);
    col[pos] = s;
}

// ---------------- main GEMM: out[i,:] = dinv[i] * (A[i,:] @ W + c) ----------------
// A row: k<256 from Xb, k>=256 from Yb (both bf16). Wt is [256 x K] bf16 (W^T).
// 128(M) x 256(N-full) tile, BK=64, 512 thr = 8 waves (2x4), XOR-swizzled LDS.
// Epilogue goes through LDS for dense 16B coalesced stores.
__global__ __launch_bounds__(512)
void k_gemm(const unsigned short* __restrict__ Xb, const unsigned short* __restrict__ Yb,
            const unsigned short* __restrict__ Wt, const float* __restrict__ cvec,
            const float* __restrict__ dinv, unsigned short* __restrict__ out,
            int M, int K) {
    __shared__ char ldsb[49152];                 // A tile 16KB @0, W tile 32KB @16384
    const int tid = threadIdx.x;
    const int lane = tid & 63;
    const int wid = tid >> 6;                    // 0..7
    const int wm = wid >> 2, wn = wid & 3;       // 2 x 4 waves
    const int l15 = lane & 15, hi = lane >> 4;
    const int row0 = blockIdx.x * 128;

    f32x4 acc[4][4] = {};
    const int KT = K / 64;
    for (int kt = 0; kt < KT; ++kt) {
        const int k0 = kt * 64;
        const unsigned short* Asrc = (k0 < 256) ? Xb : Yb;
        const int ak0 = (k0 < 256) ? k0 : k0 - 256;
        int4 ra[2], rw[4];
#pragma unroll
        for (int q = 0; q < 2; ++q) {            // A: 128 rows x 64 k = 1024 chunks
            int id = q * 512 + tid;
            int r = id >> 3, cb = id & 7;
            int grow = row0 + r; if (grow > M - 1) grow = M - 1;
            ra[q] = *(const int4*)(Asrc + (size_t)grow * 256 + ak0 + cb * 8);
        }
#pragma unroll
        for (int q = 0; q < 4; ++q) {            // W: 256 n-rows x 64 k = 2048 chunks
            int id = q * 512 + tid;
            int r = id >> 3, cb = id & 7;
            rw[q] = *(const int4*)(Wt + (size_t)r * K + k0 + cb * 8);
        }
        __syncthreads();                          // prior LDS reads done
#pragma unroll
        for (int q = 0; q < 2; ++q) {
            int id = q * 512 + tid;
            int r = id >> 3, cb = id & 7;
            int sw = (cb * 16) ^ ((r & 7) << 4);
            *(int4*)(ldsb + r * 128 + sw) = ra[q];
        }
#pragma unroll
        for (int q = 0; q < 4; ++q) {
            int id = q * 512 + tid;
            int r = id >> 3, cb = id & 7;
            int sw = (cb * 16) ^ ((r & 7) << 4);
            *(int4*)(ldsb + 16384 + r * 128 + sw) = rw[q];
        }
        __syncthreads();
#pragma unroll
        for (int kk = 0; kk < 2; ++kk) {
            bf16x8 af[4], bfr[4];
            int byte = kk * 64 + (hi << 4);
#pragma unroll
            for (int m = 0; m < 4; ++m) {
                int r = wm * 64 + m * 16 + l15;
                af[m] = *(const bf16x8*)(ldsb + r * 128 + (byte ^ ((r & 7) << 4)));
            }
#pragma unroll
            for (int n = 0; n < 4; ++n) {
                int r = wn * 64 + n * 16 + l15;
                bfr[n] = *(const bf16x8*)(ldsb + 16384 + r * 128 + (byte ^ ((r & 7) << 4)));
            }
#pragma unroll
            for (int m = 0; m < 4; ++m)
#pragma unroll
                for (int n = 0; n < 4; ++n)
                    acc[m][n] = __builtin_amdgcn_mfma_f32_16x16x32_bf16(af[m], bfr[n], acc[m][n], 0, 0, 0);
        }
    }
    // epilogue through LDS: two 64-row halves; dense int4 stores
    for (int half = 0; half < 2; ++half) {
        __syncthreads();
        if (wm == half) {
#pragma unroll
            for (int m = 0; m < 4; ++m) {
#pragma unroll
                for (int j = 0; j < 4; ++j) {
                    int rl = m * 16 + hi * 4 + j;            // 0..63
                    int grow = row0 + half * 64 + rl;
                    if (grow < M) {
                        float di = dinv[grow];
#pragma unroll
                        for (int n = 0; n < 4; ++n) {
                            int colc = wn * 64 + n * 16 + l15;
                            float v = (acc[m][n][j] + cvec[colc]) * di;
                            *(unsigned short*)(ldsb + rl * 512 + colc * 2) = f2bf(v);
                        }
                    }
                }
            }
        }
        __syncthreads();
#pragma unroll
        for (int p = 0; p < 4; ++p) {
            int rl = p * 16 + (tid >> 5);
            int cb = tid & 31;
            int grow = row0 + half * 64 + rl;
            if (grow < M)
                *(int4*)(out + (size_t)grow * 256 + cb * 8) = *(const int4*)(ldsb + rl * 512 + cb * 16);
        }
    }
}

// ---------------- aggregation: Y[i] = dinv[i]*(U[i] + sum_{j in in(i)} U[j]) + d ----------------
__global__ __launch_bounds__(256)
void k_agg(const unsigned short* __restrict__ U, const int* __restrict__ rowptr,
           const int* __restrict__ col, const float* __restrict__ dinv,
           const float* __restrict__ dvec, unsigned short* __restrict__ Y, int N) {
    int w = (blockIdx.x * 256 + threadIdx.x) >> 6;   // node per wave
    int lane = threadIdx.x & 63;
    if (w >= N) return;
    const size_t loff = (size_t)lane * 4;
    ushort4 sv = *(const ushort4*)(U + (size_t)w * 256 + loff);
    float a0 = bf2f(sv.x), a1 = bf2f(sv.y), a2 = bf2f(sv.z), a3 = bf2f(sv.w);
    int beg = rowptr[w], end = rowptr[w + 1];
    int e = beg;
    for (; e + 16 <= end; e += 16) {
        int s[16];
        ushort4 v[16];
#pragma unroll
        for (int u = 0; u < 16; ++u) s[u] = __builtin_amdgcn_readfirstlane(col[e + u]);
#pragma unroll
        for (int u = 0; u < 16; ++u) v[u] = *(const ushort4*)(U + (size_t)s[u] * 256 + loff);
#pragma unroll
        for (int u = 0; u < 16; ++u) {
            a0 += bf2f(v[u].x); a1 += bf2f(v[u].y);
            a2 += bf2f(v[u].z); a3 += bf2f(v[u].w);
        }
    }
    for (; e + 4 <= end; e += 4) {
        int s[4];
        ushort4 v[4];
#pragma unroll
        for (int u = 0; u < 4; ++u) s[u] = __builtin_amdgcn_readfirstlane(col[e + u]);
#pragma unroll
        for (int u = 0; u < 4; ++u) v[u] = *(const ushort4*)(U + (size_t)s[u] * 256 + loff);
#pragma unroll
        for (int u = 0; u < 4; ++u) {
            a0 += bf2f(v[u].x); a1 += bf2f(v[u].y);
            a2 += bf2f(v[u].z); a3 += bf2f(v[u].w);
        }
    }
    for (; e < end; ++e) {
        int s = __builtin_amdgcn_readfirstlane(col[e]);
        ushort4 v = *(const ushort4*)(U + (size_t)s * 256 + loff);
        a0 += bf2f(v.x); a1 += bf2f(v.y); a2 += bf2f(v.z); a3 += bf2f(v.w);
    }
    float di = dinv[w];
    int f = lane * 4;
    a0 = a0 * di + dvec[f + 0];
    a1 = a1 * di + dvec[f + 1];
    a2 = a2 * di + dvec[f + 2];
    a3 = a3 * di + dvec[f + 3];
    ushort4 o; o.x = f2bf(a0); o.y = f2bf(a1); o.z = f2bf(a2); o.w = f2bf(a3);
    *(ushort4*)(Y + (size_t)w * 256 + loff) = o;
}

// ---------------- pooling (batch is sorted) ----------------
__global__ __launch_bounds__(256)
void k_pool(const unsigned short* __restrict__ Y, const int* __restrict__ batch, int N,
            float* __restrict__ psum, unsigned int* __restrict__ pkey, int* __restrict__ pcnt,
            const int* __restrict__ flags) {
    int f = threadIdx.x;
    int base = blockIdx.x * 64;
    if (base >= N) return;
    int i64 = flags[1];
    int g0 = ldi(batch, base, i64); int curg = g0 < 0 ? 0 : (g0 > 63 ? 63 : g0);
    float s = 0.f, mx = -__builtin_inff(); int cnt = 0;
#pragma unroll 4
    for (int r = 0; r < 64; ++r) {
        int node = base + r;
        if (node >= N) break;
        int g = ldi(batch, node, i64); g = g < 0 ? 0 : (g > 63 ? 63 : g);
        if (g != curg) {
            atomicAdd(&psum[curg * 256 + f], s);
            atomicMax(&pkey[curg * 256 + f], fenc(mx));
            if (f == 0) atomicAdd(&pcnt[curg], cnt);
            curg = g; s = 0.f; mx = -__builtin_inff(); cnt = 0;
        }
        float v = bf2f(Y[(size_t)node * 256 + f]);
        s += v; mx = fmaxf(mx, v); ++cnt;
    }
    atomicAdd(&psum[curg * 256 + f], s);
    atomicMax(&pkey[curg * 256 + f], fenc(mx));
    if (f == 0) atomicAdd(&pcnt[curg], cnt);
}

// ---------------- classifier ----------------
__global__ __launch_bounds__(64)
void k_cls(const float* __restrict__ psum, const unsigned int* __restrict__ pkey,
           const int* __restrict__ pcnt, const void* __restrict__ clsw,
           const void* __restrict__ clsb, float* __restrict__ outf,
           unsigned short* __restrict__ outu, const int* __restrict__ flags) {
    __shared__ float pooled[256];
    int g = blockIdx.x, c = threadIdx.x;
    int f = flags[0];
    int cnt = pcnt[g];
    for (int m = c; m < 256; m += 64) {
        float mean = psum[g * 256 + m] / (float)(cnt > 0 ? cnt : 1);
        float mx = (cnt > 0) ? fdec(pkey[g * 256 + m]) : 0.f;
        pooled[m] = mean + mx;
    }
    __syncthreads();
    float a = ldf(clsb, c, f);
#pragma unroll 8
    for (int m = 0; m < 256; ++m) a += pooled[m] * ldf(clsw, (size_t)m * 64 + c, f);
    if (f) outf[g * 64 + c] = a;
    else   outu[g * 64 + c] = f2bf(a);
}

extern "C" void kernel_launch(void* const* d_in, const int* in_sizes, int n_in,
                              void* d_out, int out_size, void* d_ws, size_t ws_size,
                              hipStream_t stream) {
    const void*           X     = d_in[0];
    const int*            EI    = (const int*)d_in[1];
    const int*            BATCH = (const int*)d_in[3];
    const void*           PREW  = d_in[4];
    const void*           PREB  = d_in[5];
    const void*           GCNW  = d_in[6];
    const void*           GCNB  = d_in[7];
    const void*           CLSW  = d_in[8];
    const void*           CLSB  = d_in[9];

    const int N = in_sizes[3];
    const int E = in_sizes[1] / 2;
    const int NB = (N + 255) / 256;

    char* ws = (char*)d_ws;
    size_t off = 0;
    auto alloc = [&](size_t b) { size_t o = off; off += (b + 255) & ~(size_t)255; return o; };
    int*            flags  = (int*)(ws + alloc(256));
    float*          dinv   = (float*)(ws + alloc((size_t)N * 4));
    int*            hist   = (int*)(ws + alloc((size_t)N * 4));
    int*            cursor = (int*)(ws + alloc((size_t)N * 4));
    int*            rowptr = (int*)(ws + alloc((size_t)(N + 1) * 4));
    int*            pre    = (int*)(ws + alloc((size_t)N * 4));
    int*            bsum   = (int*)(ws + alloc((size_t)NB * 4));
    int*            boff   = (int*)(ws + alloc((size_t)NB * 4));
    int*            col    = (int*)(ws + alloc((size_t)E * 4));
    unsigned short* Pb     = (unsigned short*)(ws + alloc(4 * 65536 * 2));
    unsigned short* Gt     = (unsigned short*)(ws + alloc(4 * 65536 * 2));
    unsigned short* Wt0    = (unsigned short*)(ws + alloc(256 * 256 * 2));
    unsigned short* Wt1    = (unsigned short*)(ws + alloc(256 * 512 * 2));
    float*          cvec   = (float*)(ws + alloc(512 * 4));
    float*          dvec   = (float*)(ws + alloc(512 * 4));
    float*          psum   = (float*)(ws + alloc(64 * 256 * 4));
    unsigned int*   pkey   = (unsigned int*)(ws + alloc(64 * 256 * 4));
    int*            pcnt   = (int*)(ws + alloc(64 * 4));
    unsigned short* Xb     = (unsigned short*)(ws + alloc((size_t)N * 256 * 2));
    unsigned short* U      = (unsigned short*)(ws + alloc((size_t)N * 256 * 2));
    unsigned short* Y      = (unsigned short*)(ws + alloc((size_t)N * 256 * 2));

    int zt = 2 * N + 32768 + 64;
    k_zero<<<(zt + 255) / 256, 256, 0, stream>>>(hist, cursor, psum, pkey, pcnt, N);

    int xstride = (in_sizes[0] / 2) / 1024; if (xstride < 1) xstride = 1;
    int estride = E / 1024;                 if (estride < 1) estride = 1;
    k_detect<<<1, 256, 0, stream>>>((const unsigned short*)X, xstride, EI, estride, flags);

    size_t xelem = (size_t)N * 256;
    k_cvt<<<(int)((xelem / 8 + 255) / 256), 256, 0, stream>>>(X, Xb, xelem, flags);

    k_hist<<<(E + 255) / 256, 256, 0, stream>>>(EI, E, N, hist, flags);
    k_scan1<<<NB, 256, 0, stream>>>(hist, pre, bsum, N);
    k_scan2<<<1, 256, 0, stream>>>(bsum, boff, rowptr, NB, N);
    k_scan3<<<NB, 256, 0, stream>>>(hist, pre, boff, rowptr, dinv, N);
    k_scatter<<<(E + 255) / 256, 256, 0, stream>>>(EI, E, N, rowptr, cursor, col, flags);

    k_cvtw<<<dim3(16, 4), 256, 0, stream>>>(PREW, GCNW, Pb, Gt, flags);
    k_prepw<<<dim3(64, 3), 256, 0, stream>>>(Pb, Gt, Wt0, Wt1);
    k_prepb<<<2, 256, 0, stream>>>(PREB, Gt, GCNB, cvec, dvec, flags);

    int ggrid = (N + 127) / 128;
    k_gemm<<<ggrid, 512, 0, stream>>>(Xb, U, Wt0, cvec, dinv, U, N, 256);
    k_agg<<<(N + 3) / 4, 256, 0, stream>>>(U, rowptr, col, dinv, dvec, Y, N);
    k_gemm<<<ggrid, 512, 0, stream>>>(Xb, Y, Wt1, cvec + 256, dinv, U, N, 512);
    k_agg<<<(N + 3) / 4, 256, 0, stream>>>(U, rowptr, col, dinv, dvec + 256, Y, N);
    k_pool<<<(N + 63) / 64, 256, 0, stream>>>(Y, BATCH, N, psum, pkey, pcnt, flags);
    k_cls<<<64, 64, 0, stream>>>(psum, pkey, pcnt, CLSW, CLSB,
                                 (float*)d_out, (unsigned short*)d_out, flags);
}